// Round 2
// baseline (268.352 us; speedup 1.0000x reference)
//
#include <hip/hip_runtime.h>
#include <hip/hip_bf16.h>
#include <hip/hip_cooperative_groups.h>

namespace cg = cooperative_groups;

#define N_GRAPHS 200
#define NPG      500
#define NPGP     512
#define N_NODES_ 100000
#define N_EDGES_ 1600000
#define DIN      64
#define DG       128
#define SEQ      20
#define HL       128
#define G4       512
#define BWIN     (N_GRAPHS - SEQ + 1)  // 181
#define NBLK     256
#define EPB      (N_EDGES_/NBLK)       // 6250
#define SLOTS    64                    // mean 31.25/cell + 6 sigma
#define CAP      9216

// ---- LDS layout (single 152.6 KB arena, phase-overlaid) ----
#define OFF_DEG    0        // int[512]    indeg (sort->agg)
#define OFF_ENDX   2048     // int[512]    excl start -> incl end
#define OFF_SOS    4096     // float[512]  rsqrt(outdeg)
#define OFF_OUTD   6144     // int[512]
#define OFF_SORT   8192     // ushort[9216] = 18432
#define OFF_X      26624    // int4[4008]  = 64128 (500 rows + zero row)
#define OFF_EC     26624    // int[9216]   sort scratch, overlays X (X loaded later)
#define OFF_HPRE   90752    // int4[4096]  = 65536 (swizzled agg output)
#define SMEM_SZ    156288
// gcn-phase overlays (sort/x regions dead):
#define OFF_WLDS   8192     // ushort[8192] = 16384
#define OFF_PS     26624    // float[1024]  = 4096
#define OFF_HGS    30720    // float[128]
// part-phase overlays (everything dead):
#define OFF_PCNT   0        // int[200]
#define OFF_PBASE  800      // int[200]
#define OFF_PBUF   1600     // int[200*SLOTS] = 51200
// lstm-phase overlays (everything dead):
#define OFF_WL     0        // int4[8192] = 131072
#define OFF_GS     131072   // float[512]
#define OFF_HPI    133120   // int4[16]

typedef __attribute__((ext_vector_type(8))) short short8;
typedef __attribute__((ext_vector_type(4))) float float4v;
typedef __attribute__((ext_vector_type(2))) _Float16 half2v;

__device__ __forceinline__ float sigmoidf_(float v){ return 1.0f/(1.0f+expf(-v)); }

__device__ __forceinline__ unsigned short f2bf(float f) {
  unsigned int u = __float_as_uint(f);
  u += 0x7fffu + ((u >> 16) & 1u);
  return (unsigned short)(u >> 16);
}

__device__ __forceinline__ float h2dot(half2v a, half2v b, float c) {
#if __has_builtin(__builtin_amdgcn_fdot2)
  return __builtin_amdgcn_fdot2(a, b, c, false);
#else
  return c + (float)a.x*(float)b.x + (float)a.y*(float)b.y;
#endif
}

// One cooperative kernel, 256 blocks x 512 threads, 1 block/CU (152.6 KB LDS).
// Phase P  (all blocks): edge partition -> per-graph global segments.
// grid.sync()
// Phase G  (blocks 0..199, one graph each): counting sort (LDS) -> xprep (LDS)
//          -> aggregation (LDS->LDS) -> MFMA GEMM+ReLU+pool -> input proj.
//          Blocks 200..215: w_hh fp32->fp16 conversion.
// grid.sync()
// Phase L  (blocks 0..180): LSTM over proj windows.
__global__ __launch_bounds__(512, 1) void mega(
    const float* __restrict__ x,     const int* __restrict__ src,
    const int* __restrict__ dst,
    const float* __restrict__ w_gcn, const float* __restrict__ b_gcn,
    const float* __restrict__ w_ih,  const float* __restrict__ b_ih,
    const float* __restrict__ w_hh,  const float* __restrict__ b_hh,
    const float* __restrict__ w_fc,  const float* __restrict__ b_fc,
    int* __restrict__ gcount,        int* __restrict__ part,
    int4* __restrict__ whh16,        float* __restrict__ proj,
    float* __restrict__ out) {
  __shared__ __align__(16) char smem[SMEM_SZ];
  __shared__ int wsum[8];
  cg::grid_group grid = cg::this_grid();
  const int b = blockIdx.x, t = threadIdx.x;
  const int lane = t & 63, w = t >> 6;

  // ---------------- Phase P: partition ----------------
  {
    int* cnt  = (int*)(smem + OFF_PCNT);
    int* base = (int*)(smem + OFF_PBASE);
    int* buf  = (int*)(smem + OFF_PBUF);
    for (int i = t; i < N_GRAPHS; i += 512) cnt[i] = 0;
    __syncthreads();
    int e0 = b*EPB;
    for (int i = t; i < EPB; i += 512) {
      int s = src[e0+i], d = dst[e0+i];
      int g = s / NPG;
      int pk = ((s - g*NPG) << 9) | (d - g*NPG);
      int pos = atomicAdd(&cnt[g], 1);
      if (pos < SLOTS) buf[g*SLOTS + pos] = pk;
      else { int gp = atomicAdd(&gcount[g], 1); part[g*CAP + gp] = pk; }
    }
    __syncthreads();
    if (t < N_GRAPHS) base[t] = atomicAdd(&gcount[t], min(cnt[t], SLOTS));
    __syncthreads();
    for (int g = w; g < N_GRAPHS; g += 8) {
      int n = min(cnt[g], SLOTS);                  // n <= 64: one pass
      if (lane < n) part[g*CAP + base[g] + lane] = buf[g*SLOTS + lane];
    }
  }
  grid.sync();

  // ---------------- Phase G: per-graph sort/agg/gcn ----------------
  const int g = b;
  if (g < N_GRAPHS) {
    int*   deg    = (int*)(smem + OFF_DEG);
    int*   endx   = (int*)(smem + OFF_ENDX);
    float* soS    = (float*)(smem + OFF_SOS);
    int*   outd   = (int*)(smem + OFF_OUTD);
    unsigned short* sorted = (unsigned short*)(smem + OFF_SORT);
    int*   eC     = (int*)(smem + OFF_EC);
    int4*  xs     = (int4*)(smem + OFF_X);
    int4*  hpre   = (int4*)(smem + OFF_HPRE);

    deg[t] = 0; outd[t] = 0;
    __syncthreads();
    int nseg = gcount[g];
    int seg0 = g*CAP;
    for (int e = t; e < nseg; e += 512) {
      int p = part[seg0 + e];
      eC[e] = p;
      atomicAdd(&deg[p & 511], 1);
      atomicAdd(&outd[p >> 9], 1);
    }
    __syncthreads();
    // exclusive scan of indeg over 512 slots (wave shfl scan)
    int v = deg[t];
    int sc = v;
    #pragma unroll
    for (int o = 1; o < 64; o <<= 1) { int nn = __shfl_up(sc, o); if (lane >= o) sc += nn; }
    if (lane == 63) wsum[w] = sc;
    __syncthreads();
    int woff = 0;
    #pragma unroll
    for (int i = 0; i < 8; ++i) woff += (i < w) ? wsum[i] : 0;
    endx[t] = woff + sc - v;                       // exclusive start
    soS[t]  = rsqrtf((float)max(outd[t], 1));
    __syncthreads();
    for (int e = t; e < nseg; e += 512) {
      int p = eC[e];
      int pos = atomicAdd(&endx[p & 511], 1);      // -> inclusive end
      sorted[pos] = (unsigned short)(p >> 9);
    }
    __syncthreads();
    // xprep: x * outdeg^-1/2 -> bf16 rows in LDS (+ zero row 500)
    const float4* xg = ((const float4*)x) + (size_t)g*8000;
    ushort4* xd = (ushort4*)xs;
    for (int i = t; i < 8000; i += 512) {
      float4 vv = xg[i];
      float s2 = soS[i >> 4];
      ushort4 u;
      u.x = f2bf(vv.x*s2); u.y = f2bf(vv.y*s2); u.z = f2bf(vv.z*s2); u.w = f2bf(vv.w*s2);
      xd[i] = u;
    }
    if (t < 16) xd[8000 + t] = make_ushort4(0,0,0,0);
    __syncthreads();
    // aggregation: 64 groups of 8 lanes, 8 nodes/group, edges in chunks of 8
    int g8 = lane >> 3, fl = lane & 7;
    int G = w*8 + g8;
    for (int sI = 0; sI < 8; ++sI) {
      int nl = sI*64 + G;
      int4 outv = make_int4(0,0,0,0);
      if (nl < NPG) {
        int end = endx[nl], dgr = deg[nl], st = end - dgr;
        float aHi[4] = {0.f,0.f,0.f,0.f};
        float aLo[4] = {0.f,0.f,0.f,0.f};
        for (int c0 = 0; c0 < dgr; c0 += 8) {
          int ev = 500;                            // zero row
          if (c0 + fl < dgr) ev = (int)sorted[st + c0 + fl];
          #pragma unroll
          for (int j = 0; j < 8; ++j) {
            int se = __shfl(ev, (g8 << 3) + j);
            int4 vv = xs[(se << 3) + fl];
            aHi[0] += __uint_as_float((unsigned)vv.x & 0xffff0000u);
            aLo[0] += __uint_as_float((unsigned)vv.x << 16);
            aHi[1] += __uint_as_float((unsigned)vv.y & 0xffff0000u);
            aLo[1] += __uint_as_float((unsigned)vv.y << 16);
            aHi[2] += __uint_as_float((unsigned)vv.z & 0xffff0000u);
            aLo[2] += __uint_as_float((unsigned)vv.z << 16);
            aHi[3] += __uint_as_float((unsigned)vv.w & 0xffff0000u);
            aLo[3] += __uint_as_float((unsigned)vv.w << 16);
          }
        }
        float sn = rsqrtf((float)max(dgr, 1));
        outv.x = (int)(((unsigned)f2bf(aLo[0]*sn)) | ((unsigned)f2bf(aHi[0]*sn) << 16));
        outv.y = (int)(((unsigned)f2bf(aLo[1]*sn)) | ((unsigned)f2bf(aHi[1]*sn) << 16));
        outv.z = (int)(((unsigned)f2bf(aLo[2]*sn)) | ((unsigned)f2bf(aHi[2]*sn) << 16));
        outv.w = (int)(((unsigned)f2bf(aLo[3]*sn)) | ((unsigned)f2bf(aHi[3]*sn) << 16));
      }
      // XOR-swizzled 16B-block index: conflict-free here AND in the GEMM read
      hpre[(nl << 3) + (fl ^ (nl & 7))] = outv;
    }
    __syncthreads();
    // ---- GCN GEMM + ReLU + mean pool (A from LDS hpre, swizzled) ----
    unsigned short* wLds = (unsigned short*)(smem + OFF_WLDS);
    float* pS  = (float*)(smem + OFF_PS);
    float* hgS = (float*)(smem + OFF_HGS);
    for (int i = t; i < 2048; i += 512) {
      float4 w4 = ((const float4*)w_gcn)[i];
      int k = i >> 5, c4 = (i & 31) << 2;
      int h = k >> 5, j = k & 7, lhi = ((k >> 3) & 3) << 4;
      float vvv[4] = {w4.x, w4.y, w4.z, w4.w};
      #pragma unroll
      for (int u = 0; u < 4; ++u) {
        int n = c4 + u;
        int idx = ((n >> 4)*2 + h)*64 + lhi + (n & 15);
        wLds[idx*8 + j] = f2bf(vvv[u]);
      }
    }
    __syncthreads();
    int quad = lane >> 4, l15 = lane & 15;
    float bcol[8];
    #pragma unroll
    for (int nt = 0; nt < 8; ++nt) bcol[nt] = b_gcn[nt*16 + l15];
    float psum[8] = {0.f,0.f,0.f,0.f,0.f,0.f,0.f,0.f};
    for (int i = 0; i < 4; ++i) {
      int row0 = (w + 8*i) << 4;
      int r = row0 + l15;
      int4 a0i = hpre[(r << 3) + (quad ^ (r & 7))];
      int4 a1i = hpre[(r << 3) + ((quad + 4) ^ (r & 7))];
      short8 a0 = *(const short8*)&a0i;
      short8 a1 = *(const short8*)&a1i;
      #pragma unroll
      for (int nt = 0; nt < 8; ++nt) {
        short8 b0 = *((const short8*)&wLds[((nt*2+0)*64 + lane)*8]);
        short8 b1 = *((const short8*)&wLds[((nt*2+1)*64 + lane)*8]);
        float4v acc = {0.f, 0.f, 0.f, 0.f};
        acc = __builtin_amdgcn_mfma_f32_16x16x32_bf16(a0, b0, acc, 0, 0, 0);
        acc = __builtin_amdgcn_mfma_f32_16x16x32_bf16(a1, b1, acc, 0, 0, 0);
        #pragma unroll
        for (int r4 = 0; r4 < 4; ++r4) {
          int node = row0 + quad*4 + r4;
          float vvv = acc[r4] + bcol[nt];
          psum[nt] += (node < NPG) ? fmaxf(vvv, 0.f) : 0.f;
        }
      }
    }
    #pragma unroll
    for (int nt = 0; nt < 8; ++nt) {
      float vvv = psum[nt];
      vvv += __shfl_xor(vvv, 16);
      vvv += __shfl_xor(vvv, 32);
      if (lane < 16) pS[w*DG + nt*16 + lane] = vvv;
    }
    __syncthreads();
    if (t < DG) {
      float sum = 0.f;
      #pragma unroll
      for (int w8 = 0; w8 < 8; ++w8) sum += pS[w8*DG + t];
      hgS[t] = sum * (1.0f/NPG);
    }
    __syncthreads();
    // fused input projection: thread t -> row t of w_ih
    {
      const float4* wr = (const float4*)(w_ih + (size_t)t*HL);
      const float4* hv = (const float4*)hgS;
      float acc = b_ih[t];
      #pragma unroll
      for (int k4 = 0; k4 < 32; ++k4) {
        float4 w4 = wr[k4]; float4 h4 = hv[k4];
        acc += w4.x*h4.x + w4.y*h4.y + w4.z*h4.z + w4.w*h4.w;
      }
      proj[(size_t)g*G4 + t] = acc;
    }
  } else if (g >= N_GRAPHS && g < N_GRAPHS + 16) {
    // idle blocks convert w_hh fp32 -> fp16 (layout: i = k4*512 + r)
    int i = ((g - N_GRAPHS) << 9) + t;
    int k4 = i >> 9, r = i & 511;
    const float4* wp = (const float4*)(w_hh + (size_t)r*HL + k4*8);
    float4 w0 = wp[0], w1 = wp[1];
    half2v p0 = {(_Float16)w0.x, (_Float16)w0.y};
    half2v p1 = {(_Float16)w0.z, (_Float16)w0.w};
    half2v p2 = {(_Float16)w1.x, (_Float16)w1.y};
    half2v p3 = {(_Float16)w1.z, (_Float16)w1.w};
    int4 pk;
    pk.x = __builtin_bit_cast(int, p0); pk.y = __builtin_bit_cast(int, p1);
    pk.z = __builtin_bit_cast(int, p2); pk.w = __builtin_bit_cast(int, p3);
    whh16[i] = pk;
  }
  grid.sync();

  // ---------------- Phase L: LSTM ----------------
  if (b < BWIN) {
    int4*  wL  = (int4*)(smem + OFF_WL);
    float* gS  = (float*)(smem + OFF_GS);
    int4*  hPi = (int4*)(smem + OFF_HPI);
    for (int i = t; i < 16*512; i += 512) wL[i] = whh16[i];
    if (t < 16) hPi[t] = make_int4(0,0,0,0);
    float bh = b_hh[t];
    float c0 = 0.f, c1 = 0.f;
    __syncthreads();
    for (int l = 0; l < SEQ; ++l) {
      float a0 = proj[(size_t)(b+l)*G4 + t] + bh;
      float a1 = 0.f, a2 = 0.f, a3 = 0.f;
      #pragma unroll
      for (int k4 = 0; k4 < 16; k4 += 4) {
        int4 wv0 = wL[((k4+0) << 9) + t]; int4 hv0 = hPi[k4+0];
        int4 wv1 = wL[((k4+1) << 9) + t]; int4 hv1 = hPi[k4+1];
        int4 wv2 = wL[((k4+2) << 9) + t]; int4 hv2 = hPi[k4+2];
        int4 wv3 = wL[((k4+3) << 9) + t]; int4 hv3 = hPi[k4+3];
        a0 = h2dot(__builtin_bit_cast(half2v, wv0.x), __builtin_bit_cast(half2v, hv0.x), a0);
        a0 = h2dot(__builtin_bit_cast(half2v, wv0.y), __builtin_bit_cast(half2v, hv0.y), a0);
        a0 = h2dot(__builtin_bit_cast(half2v, wv0.z), __builtin_bit_cast(half2v, hv0.z), a0);
        a0 = h2dot(__builtin_bit_cast(half2v, wv0.w), __builtin_bit_cast(half2v, hv0.w), a0);
        a1 = h2dot(__builtin_bit_cast(half2v, wv1.x), __builtin_bit_cast(half2v, hv1.x), a1);
        a1 = h2dot(__builtin_bit_cast(half2v, wv1.y), __builtin_bit_cast(half2v, hv1.y), a1);
        a1 = h2dot(__builtin_bit_cast(half2v, wv1.z), __builtin_bit_cast(half2v, hv1.z), a1);
        a1 = h2dot(__builtin_bit_cast(half2v, wv1.w), __builtin_bit_cast(half2v, hv1.w), a1);
        a2 = h2dot(__builtin_bit_cast(half2v, wv2.x), __builtin_bit_cast(half2v, hv2.x), a2);
        a2 = h2dot(__builtin_bit_cast(half2v, wv2.y), __builtin_bit_cast(half2v, hv2.y), a2);
        a2 = h2dot(__builtin_bit_cast(half2v, wv2.z), __builtin_bit_cast(half2v, hv2.z), a2);
        a2 = h2dot(__builtin_bit_cast(half2v, wv2.w), __builtin_bit_cast(half2v, hv2.w), a2);
        a3 = h2dot(__builtin_bit_cast(half2v, wv3.x), __builtin_bit_cast(half2v, hv3.x), a3);
        a3 = h2dot(__builtin_bit_cast(half2v, wv3.y), __builtin_bit_cast(half2v, hv3.y), a3);
        a3 = h2dot(__builtin_bit_cast(half2v, wv3.z), __builtin_bit_cast(half2v, hv3.z), a3);
        a3 = h2dot(__builtin_bit_cast(half2v, wv3.w), __builtin_bit_cast(half2v, hv3.w), a3);
      }
      gS[t] = (a0 + a1) + (a2 + a3);
      __syncthreads();
      if (t < 64) {
        int j0 = 2*t, j1 = 2*t + 1;
        float i0 = sigmoidf_(gS[j0]),      i1 = sigmoidf_(gS[j1]);
        float f0 = sigmoidf_(gS[HL+j0]),   f1 = sigmoidf_(gS[HL+j1]);
        float g0 = tanhf(gS[2*HL+j0]),     g1 = tanhf(gS[2*HL+j1]);
        float o0 = sigmoidf_(gS[3*HL+j0]), o1 = sigmoidf_(gS[3*HL+j1]);
        c0 = f0*c0 + i0*g0;
        c1 = f1*c1 + i1*g1;
        float h0 = o0 * tanhf(c0);
        float h1 = o1 * tanhf(c1);
        half2v hp = {(_Float16)h0, (_Float16)h1};
        ((int*)hPi)[t] = __builtin_bit_cast(int, hp);
        if (l == SEQ-1) {
          float s = h0*w_fc[j0] + h1*w_fc[j1];
          #pragma unroll
          for (int off = 32; off > 0; off >>= 1) s += __shfl_down(s, off);
          if (t == 0) out[b] = s + b_fc[0];
        }
      }
      __syncthreads();
    }
  }
}

extern "C" void kernel_launch(void* const* d_in, const int* in_sizes, int n_in,
                              void* d_out, int out_size, void* d_ws, size_t ws_size,
                              hipStream_t stream) {
  const float* x     = (const float*)d_in[0];
  const int*   src   = (const int*)d_in[1];
  const int*   dst   = (const int*)d_in[2];
  const float* w_gcn = (const float*)d_in[4];
  const float* b_gcn = (const float*)d_in[5];
  const float* w_ih  = (const float*)d_in[6];
  const float* w_hh  = (const float*)d_in[7];
  const float* b_ih  = (const float*)d_in[8];
  const float* b_hh  = (const float*)d_in[9];
  const float* w_fc  = (const float*)d_in[10];
  const float* b_fc  = (const float*)d_in[11];
  float* out = (float*)d_out;

  char* ws = (char*)d_ws;
  size_t off = 0;
  auto alloc = [&](size_t bytes) -> void* {
    void* p = ws + off; off += (bytes + 255) & ~(size_t)255; return p;
  };
  int*   gcount = (int*)alloc((size_t)N_GRAPHS*4);
  int*   part   = (int*)alloc((size_t)N_GRAPHS*CAP*4);
  int4*  whh16  = (int4*)alloc((size_t)8192*16);
  float* proj   = (float*)alloc((size_t)N_GRAPHS*G4*4);
  (void)ws_size; (void)in_sizes; (void)n_in; (void)out_size;

  hipMemsetAsync(gcount, 0, (size_t)N_GRAPHS*4, stream);
  void* args[16] = {
    (void*)&x, (void*)&src, (void*)&dst,
    (void*)&w_gcn, (void*)&b_gcn,
    (void*)&w_ih, (void*)&b_ih,
    (void*)&w_hh, (void*)&b_hh,
    (void*)&w_fc, (void*)&b_fc,
    (void*)&gcount, (void*)&part, (void*)&whh16, (void*)&proj,
    (void*)&out
  };
  hipLaunchCooperativeKernel((void*)mega, dim3(NBLK), dim3(512), args, 0, stream);
}

// Round 3
// 188.721 us; speedup vs baseline: 1.4220x; 1.4220x over previous
//
#include <hip/hip_runtime.h>
#include <hip/hip_bf16.h>

#define N_GRAPHS 200
#define NPG      500
#define NPGP     512
#define N_NODES_ 100000
#define N_EDGES_ 1600000
#define DIN      64
#define DG       128
#define SEQ      20
#define HL       128
#define G4       512
#define BWIN     (N_GRAPHS - SEQ + 1)  // 181
#define NPART    512
#define EPB      (N_EDGES_/NPART)      // 3125
#define SLOTS    48
#define CAP      9216

typedef __attribute__((ext_vector_type(8))) short short8;
typedef __attribute__((ext_vector_type(4))) float float4v;
typedef __attribute__((ext_vector_type(2))) _Float16 half2v;

__device__ __forceinline__ float sigmoidf_(float v){ return 1.0f/(1.0f+expf(-v)); }

__device__ __forceinline__ unsigned short f2bf(float f) {
  unsigned int u = __float_as_uint(f);
  u += 0x7fffu + ((u >> 16) & 1u);
  return (unsigned short)(u >> 16);
}

__device__ __forceinline__ float h2dot(half2v a, half2v b, float c) {
#if __has_builtin(__builtin_amdgcn_fdot2)
  return __builtin_amdgcn_fdot2(a, b, c, false);
#else
  return c + (float)a.x*(float)b.x + (float)a.y*(float)b.y;
#endif
}

// K1: edge partition (round-1 proven) + w_hh fp32->fp16 conversion on blocks 0..31.
__global__ __launch_bounds__(256) void k_part(const int* __restrict__ src,
                                              const int* __restrict__ dst,
                                              const float* __restrict__ w_hh,
                                              int* __restrict__ gcount,
                                              int* __restrict__ part,
                                              int4* __restrict__ whh16) {
  __shared__ int cnt[N_GRAPHS];
  __shared__ int base[N_GRAPHS];
  __shared__ int buf[N_GRAPHS][SLOTS];   // 38.4 KB
  int b = blockIdx.x, t = threadIdx.x;
  if (b < 32) {                          // whh16[i], i = k4*512 + r
    int i = b*256 + t;
    int k4 = i >> 9, r = i & 511;
    const float4* wp = (const float4*)(w_hh + (size_t)r*HL + k4*8);
    float4 w0 = wp[0], w1 = wp[1];
    half2v p0 = {(_Float16)w0.x, (_Float16)w0.y};
    half2v p1 = {(_Float16)w0.z, (_Float16)w0.w};
    half2v p2 = {(_Float16)w1.x, (_Float16)w1.y};
    half2v p3 = {(_Float16)w1.z, (_Float16)w1.w};
    int4 pk;
    pk.x = __builtin_bit_cast(int, p0); pk.y = __builtin_bit_cast(int, p1);
    pk.z = __builtin_bit_cast(int, p2); pk.w = __builtin_bit_cast(int, p3);
    whh16[i] = pk;
  }
  for (int g = t; g < N_GRAPHS; g += 256) cnt[g] = 0;
  __syncthreads();
  int e0 = b*EPB;
  for (int i = t; i < EPB; i += 256) {
    int s = src[e0+i], d = dst[e0+i];
    int g = s / NPG;
    int pk = ((s - g*NPG) << 9) | (d - g*NPG);
    int pos = atomicAdd(&cnt[g], 1);
    if (pos < SLOTS) buf[g][pos] = pk;
    else { int gp = atomicAdd(&gcount[g], 1); part[g*CAP + gp] = pk; }
  }
  __syncthreads();
  if (t < N_GRAPHS) base[t] = atomicAdd(&gcount[t], min(cnt[t], SLOTS));
  __syncthreads();
  int w = t >> 6, lane = t & 63;
  for (int g = w; g < N_GRAPHS; g += 4) {
    int n = min(cnt[g], SLOTS);
    if (lane < n) part[g*CAP + base[g] + lane] = buf[g][lane];
  }
}

// K2: per-graph counting sort. Round-change: scatter into LDS then coalesced
// 8B flush (was 1.6M scattered 2B global stores); xprep removed (k_aggcn
// stages x directly) -> only per-node norms (so_g) written. 61.5 KB LDS,
// 2 blocks/CU.
__global__ __launch_bounds__(512) void k_sort(const int* __restrict__ gcount,
    const int* __restrict__ part,
    unsigned short* __restrict__ sorted_all,
    int* __restrict__ e_end, int* __restrict__ e_deg,
    float* __restrict__ so_g) {
  __shared__ int indeg[512], outdeg[512], off[512];
  __shared__ int wsum[8];
  __shared__ int eC[CAP];                // 36.9 KB
  __shared__ unsigned short sl[CAP];     // 18.4 KB
  int g = blockIdx.x, t = threadIdx.x;
  int lane = t & 63, w = t >> 6;
  indeg[t] = 0; outdeg[t] = 0;
  __syncthreads();
  int nseg = gcount[g], seg0 = g*CAP;
  for (int e = t; e < nseg; e += 512) {
    int p = part[seg0 + e];
    eC[e] = p;
    atomicAdd(&indeg[p & 511], 1);
    atomicAdd(&outdeg[p >> 9], 1);
  }
  __syncthreads();
  int v = indeg[t], sc = v;
  #pragma unroll
  for (int o = 1; o < 64; o <<= 1) { int nn = __shfl_up(sc, o); if (lane >= o) sc += nn; }
  if (lane == 63) wsum[w] = sc;
  __syncthreads();
  int woff = 0;
  #pragma unroll
  for (int i = 0; i < 8; ++i) woff += (i < w) ? wsum[i] : 0;
  off[t] = woff + sc - v;                // exclusive start
  so_g[g*512 + t] = rsqrtf((float)max(outdeg[t], 1));
  if (t < NPG) e_deg[g*NPG + t] = v;
  __syncthreads();
  for (int e = t; e < nseg; e += 512) {
    int p = eC[e];
    int pos = atomicAdd(&off[p & 511], 1);
    sl[pos] = (unsigned short)(p >> 9);
  }
  __syncthreads();
  if (t < NPG) e_end[g*NPG + t] = seg0 + off[t];   // inclusive end
  int n4 = nseg >> 2;
  ushort4* dv = (ushort4*)(sorted_all + seg0);     // seg0*2 % 8 == 0
  const ushort4* sv = (const ushort4*)sl;
  for (int i = t; i < n4; i += 512) dv[i] = sv[i];
  for (int i = (n4 << 2) + t; i < nseg; i += 512) sorted_all[seg0 + i] = sl[i];
}

// K3: fused xprep + aggregation + MFMA GEMM + ReLU + mean-pool + input proj.
// One block per graph, 147 KB LDS (1 block/CU). x staged f32->bf16*so into
// LDS; agg is LDS-throughput-bound with 8-deep unrolled reads + prefetched
// edge indices; hpre stays in LDS (XOR-swizzled) and feeds the MFMA directly.
// Removes xsb (25.6 MB) and hpreb (26 MB) global round-trips.
__global__ __launch_bounds__(512, 1) void k_aggcn(
    const float* __restrict__ x, const float* __restrict__ so_g,
    const int* __restrict__ e_end, const int* __restrict__ e_deg,
    const unsigned short* __restrict__ sorted_all,
    const float* __restrict__ w_gcn, const float* __restrict__ b_gcn,
    const float* __restrict__ w_ih, const float* __restrict__ b_ih,
    float* __restrict__ proj) {
  __shared__ __align__(16) int4 xs[4008];      // 64.1 KB (500 rows + zero row)
  __shared__ __align__(16) int4 hpre[4096];    // 64 KB swizzled
  __shared__ unsigned short wLds[8192];        // 16 KB
  __shared__ float pS[1024];
  __shared__ __align__(16) float hgS[128];
  int g = blockIdx.x, t = threadIdx.x;
  int lane = t & 63, w = t >> 6;
  // stage x * so -> bf16 rows in LDS
  const float4* xg = ((const float4*)x) + (size_t)g*8000;
  const float* sog = so_g + g*512;
  ushort4* xd = (ushort4*)xs;
  for (int i = t; i < 8000; i += 512) {
    float4 vv = xg[i];
    float s2 = sog[i >> 4];
    ushort4 u;
    u.x = f2bf(vv.x*s2); u.y = f2bf(vv.y*s2); u.z = f2bf(vv.z*s2); u.w = f2bf(vv.w*s2);
    xd[i] = u;
  }
  if (t < 16) xd[8000 + t] = make_ushort4(0,0,0,0);
  // stage w_gcn (coalesced float4)
  for (int i = t; i < 2048; i += 512) {
    float4 w4 = ((const float4*)w_gcn)[i];
    int k = i >> 5, c4 = (i & 31) << 2;
    int h = k >> 5, j = k & 7, lhi = ((k >> 3) & 3) << 4;
    float vvv[4] = {w4.x, w4.y, w4.z, w4.w};
    #pragma unroll
    for (int u = 0; u < 4; ++u) {
      int n = c4 + u;
      int idx = ((n >> 4)*2 + h)*64 + lhi + (n & 15);
      wLds[idx*8 + j] = f2bf(vvv[u]);
    }
  }
  __syncthreads();
  // aggregation: 64 groups x 8 lanes, 8 nodes/group
  int g8 = lane >> 3, fl = lane & 7;
  int G = w*8 + g8;
  for (int sI = 0; sI < 8; ++sI) {
    int nl = sI*64 + G;
    int4 outv = make_int4(0,0,0,0);
    if (nl < NPG) {
      int n = g*NPG + nl;
      int end = e_end[n], dgr = e_deg[n], st = end - dgr;
      float aHi[4] = {0.f,0.f,0.f,0.f};
      float aLo[4] = {0.f,0.f,0.f,0.f};
      int ev = (fl < dgr) ? (int)sorted_all[st + fl] : 500;
      for (int c0 = 0; c0 < dgr; c0 += 8) {
        int nc = c0 + 8;
        int evn = (nc + fl < dgr) ? (int)sorted_all[st + nc + fl] : 500;
        #pragma unroll
        for (int j = 0; j < 8; ++j) {
          int se = __shfl(ev, (g8 << 3) + j);
          int4 vv = xs[(se << 3) + fl];
          aHi[0] += __uint_as_float((unsigned)vv.x & 0xffff0000u);
          aLo[0] += __uint_as_float((unsigned)vv.x << 16);
          aHi[1] += __uint_as_float((unsigned)vv.y & 0xffff0000u);
          aLo[1] += __uint_as_float((unsigned)vv.y << 16);
          aHi[2] += __uint_as_float((unsigned)vv.z & 0xffff0000u);
          aLo[2] += __uint_as_float((unsigned)vv.z << 16);
          aHi[3] += __uint_as_float((unsigned)vv.w & 0xffff0000u);
          aLo[3] += __uint_as_float((unsigned)vv.w << 16);
        }
        ev = evn;
      }
      float sn = rsqrtf((float)max(dgr, 1));
      outv.x = (int)(((unsigned)f2bf(aLo[0]*sn)) | ((unsigned)f2bf(aHi[0]*sn) << 16));
      outv.y = (int)(((unsigned)f2bf(aLo[1]*sn)) | ((unsigned)f2bf(aHi[1]*sn) << 16));
      outv.z = (int)(((unsigned)f2bf(aLo[2]*sn)) | ((unsigned)f2bf(aHi[2]*sn) << 16));
      outv.w = (int)(((unsigned)f2bf(aLo[3]*sn)) | ((unsigned)f2bf(aHi[3]*sn) << 16));
    }
    hpre[(nl << 3) + (fl ^ (nl & 7))] = outv;   // swizzled, conflict-free
  }
  __syncthreads();
  // MFMA GEMM + ReLU + pool
  int quad = lane >> 4, l15 = lane & 15;
  float bcol[8];
  #pragma unroll
  for (int nt = 0; nt < 8; ++nt) bcol[nt] = b_gcn[nt*16 + l15];
  float psum[8] = {0.f,0.f,0.f,0.f,0.f,0.f,0.f,0.f};
  for (int i = 0; i < 4; ++i) {
    int row0 = (w + 8*i) << 4;
    int r = row0 + l15;
    int4 a0i = hpre[(r << 3) + (quad ^ (r & 7))];
    int4 a1i = hpre[(r << 3) + ((quad + 4) ^ (r & 7))];
    short8 a0 = *(const short8*)&a0i;
    short8 a1 = *(const short8*)&a1i;
    #pragma unroll
    for (int nt = 0; nt < 8; ++nt) {
      short8 b0 = *((const short8*)&wLds[((nt*2+0)*64 + lane)*8]);
      short8 b1 = *((const short8*)&wLds[((nt*2+1)*64 + lane)*8]);
      float4v acc = {0.f, 0.f, 0.f, 0.f};
      acc = __builtin_amdgcn_mfma_f32_16x16x32_bf16(a0, b0, acc, 0, 0, 0);
      acc = __builtin_amdgcn_mfma_f32_16x16x32_bf16(a1, b1, acc, 0, 0, 0);
      #pragma unroll
      for (int r4 = 0; r4 < 4; ++r4) {
        int node = row0 + quad*4 + r4;
        float vvv = acc[r4] + bcol[nt];
        psum[nt] += (node < NPG) ? fmaxf(vvv, 0.f) : 0.f;
      }
    }
  }
  #pragma unroll
  for (int nt = 0; nt < 8; ++nt) {
    float vvv = psum[nt];
    vvv += __shfl_xor(vvv, 16);
    vvv += __shfl_xor(vvv, 32);
    if (lane < 16) pS[w*DG + nt*16 + lane] = vvv;
  }
  __syncthreads();
  if (t < DG) {
    float sum = 0.f;
    #pragma unroll
    for (int w8 = 0; w8 < 8; ++w8) sum += pS[w8*DG + t];
    hgS[t] = sum * (1.0f/NPG);
  }
  __syncthreads();
  // fused input projection: thread t -> row t of w_ih
  const float4* wr = (const float4*)(w_ih + (size_t)t*HL);
  const float4* hv = (const float4*)hgS;
  float acc = b_ih[t];
  #pragma unroll
  for (int k4 = 0; k4 < 32; ++k4) {
    float4 w4 = wr[k4]; float4 h4 = hv[k4];
    acc += w4.x*h4.x + w4.y*h4.y + w4.z*h4.z + w4.w*h4.w;
  }
  proj[(size_t)g*G4 + t] = acc;
}

// K4: LSTM. Round-change: w_hh fp16 in REGISTERS (thread t owns gate-row t,
// 16 int4 = 64 VGPR), h-state broadcast from tiny LDS (same-address reads
// broadcast, no bank cost). Kills the 128 KB LDS array and the per-step
// 128 KB LDS sweep (was ~1024 cyc/step of pure LDS BW).
__global__ __launch_bounds__(512) void k_lstm(const float* __restrict__ proj,
    const int4* __restrict__ whh16, const float* __restrict__ b_hh,
    const float* __restrict__ w_fc, const float* __restrict__ b_fc,
    float* __restrict__ out) {
  __shared__ float gS[G4];
  __shared__ __align__(16) int4 hPi[16];  // 128 fp16 packed h state
  int b = blockIdx.x, t = threadIdx.x;
  int4 W[16];
  #pragma unroll
  for (int k4 = 0; k4 < 16; ++k4) W[k4] = whh16[(k4 << 9) + t];   // coalesced
  if (t < 16) hPi[t] = make_int4(0,0,0,0);
  float bh = b_hh[t];
  float c0 = 0.f, c1 = 0.f;
  __syncthreads();
  for (int l = 0; l < SEQ; ++l) {
    float a0 = proj[(size_t)(b+l)*G4 + t] + bh;
    float a1 = 0.f, a2 = 0.f, a3 = 0.f;
    #pragma unroll
    for (int k4 = 0; k4 < 16; k4 += 4) {
      int4 hv0 = hPi[k4+0]; int4 hv1 = hPi[k4+1];
      int4 hv2 = hPi[k4+2]; int4 hv3 = hPi[k4+3];
      a0 = h2dot(__builtin_bit_cast(half2v, W[k4+0].x), __builtin_bit_cast(half2v, hv0.x), a0);
      a0 = h2dot(__builtin_bit_cast(half2v, W[k4+0].y), __builtin_bit_cast(half2v, hv0.y), a0);
      a0 = h2dot(__builtin_bit_cast(half2v, W[k4+0].z), __builtin_bit_cast(half2v, hv0.z), a0);
      a0 = h2dot(__builtin_bit_cast(half2v, W[k4+0].w), __builtin_bit_cast(half2v, hv0.w), a0);
      a1 = h2dot(__builtin_bit_cast(half2v, W[k4+1].x), __builtin_bit_cast(half2v, hv1.x), a1);
      a1 = h2dot(__builtin_bit_cast(half2v, W[k4+1].y), __builtin_bit_cast(half2v, hv1.y), a1);
      a1 = h2dot(__builtin_bit_cast(half2v, W[k4+1].z), __builtin_bit_cast(half2v, hv1.z), a1);
      a1 = h2dot(__builtin_bit_cast(half2v, W[k4+1].w), __builtin_bit_cast(half2v, hv1.w), a1);
      a2 = h2dot(__builtin_bit_cast(half2v, W[k4+2].x), __builtin_bit_cast(half2v, hv2.x), a2);
      a2 = h2dot(__builtin_bit_cast(half2v, W[k4+2].y), __builtin_bit_cast(half2v, hv2.y), a2);
      a2 = h2dot(__builtin_bit_cast(half2v, W[k4+2].z), __builtin_bit_cast(half2v, hv2.z), a2);
      a2 = h2dot(__builtin_bit_cast(half2v, W[k4+2].w), __builtin_bit_cast(half2v, hv2.w), a2);
      a3 = h2dot(__builtin_bit_cast(half2v, W[k4+3].x), __builtin_bit_cast(half2v, hv3.x), a3);
      a3 = h2dot(__builtin_bit_cast(half2v, W[k4+3].y), __builtin_bit_cast(half2v, hv3.y), a3);
      a3 = h2dot(__builtin_bit_cast(half2v, W[k4+3].z), __builtin_bit_cast(half2v, hv3.z), a3);
      a3 = h2dot(__builtin_bit_cast(half2v, W[k4+3].w), __builtin_bit_cast(half2v, hv3.w), a3);
    }
    gS[t] = (a0 + a1) + (a2 + a3);
    __syncthreads();
    if (t < 64) {
      int j0 = 2*t, j1 = 2*t + 1;
      float i0 = sigmoidf_(gS[j0]),      i1 = sigmoidf_(gS[j1]);
      float f0 = sigmoidf_(gS[HL+j0]),   f1 = sigmoidf_(gS[HL+j1]);
      float g0 = tanhf(gS[2*HL+j0]),     g1 = tanhf(gS[2*HL+j1]);
      float o0 = sigmoidf_(gS[3*HL+j0]), o1 = sigmoidf_(gS[3*HL+j1]);
      c0 = f0*c0 + i0*g0;
      c1 = f1*c1 + i1*g1;
      float h0 = o0 * tanhf(c0);
      float h1 = o1 * tanhf(c1);
      half2v hp = {(_Float16)h0, (_Float16)h1};
      ((int*)hPi)[t] = __builtin_bit_cast(int, hp);
      if (l == SEQ-1) {
        float s = h0*w_fc[j0] + h1*w_fc[j1];
        #pragma unroll
        for (int off = 32; off > 0; off >>= 1) s += __shfl_down(s, off);
        if (t == 0) out[b] = s + b_fc[0];
      }
    }
    __syncthreads();
  }
}

extern "C" void kernel_launch(void* const* d_in, const int* in_sizes, int n_in,
                              void* d_out, int out_size, void* d_ws, size_t ws_size,
                              hipStream_t stream) {
  const float* x     = (const float*)d_in[0];
  const int*   src   = (const int*)d_in[1];
  const int*   dst   = (const int*)d_in[2];
  const float* w_gcn = (const float*)d_in[4];
  const float* b_gcn = (const float*)d_in[5];
  const float* w_ih  = (const float*)d_in[6];
  const float* w_hh  = (const float*)d_in[7];
  const float* b_ih  = (const float*)d_in[8];
  const float* b_hh  = (const float*)d_in[9];
  const float* w_fc  = (const float*)d_in[10];
  const float* b_fc  = (const float*)d_in[11];
  float* out = (float*)d_out;

  char* ws = (char*)d_ws;
  size_t off = 0;
  auto alloc = [&](size_t bytes) -> void* {
    void* p = ws + off; off += (bytes + 255) & ~(size_t)255; return p;
  };
  int* gcount  = (int*)alloc((size_t)N_GRAPHS*4);
  int* part    = (int*)alloc((size_t)N_GRAPHS*CAP*4);
  unsigned short* sorted_all = (unsigned short*)alloc((size_t)N_GRAPHS*CAP*2);
  int* e_end   = (int*)alloc((size_t)N_NODES_*4);
  int* e_deg   = (int*)alloc((size_t)N_NODES_*4);
  float* so_g  = (float*)alloc((size_t)N_GRAPHS*512*4);
  int4* whh16  = (int4*)alloc((size_t)8192*16);
  float* proj  = (float*)alloc((size_t)N_GRAPHS*G4*4);
  (void)ws_size; (void)in_sizes; (void)n_in; (void)out_size;

  hipMemsetAsync(gcount, 0, (size_t)N_GRAPHS*4, stream);
  k_part<<<NPART, 256, 0, stream>>>(src, dst, w_hh, gcount, part, whh16);
  k_sort<<<N_GRAPHS, 512, 0, stream>>>(gcount, part, sorted_all, e_end, e_deg, so_g);
  k_aggcn<<<N_GRAPHS, 512, 0, stream>>>(x, so_g, e_end, e_deg, sorted_all,
                                        w_gcn, b_gcn, w_ih, b_ih, proj);
  k_lstm<<<BWIN, 512, 0, stream>>>(proj, whh16, b_hh, w_fc, b_fc, out);
}

// Round 4
// 182.602 us; speedup vs baseline: 1.4696x; 1.0335x over previous
//
#include <hip/hip_runtime.h>
#include <hip/hip_bf16.h>

#define N_GRAPHS 200
#define NPG      500
#define NPGP     512
#define N_NODES_ 100000
#define N_EDGES_ 1600000
#define DIN      64
#define DG       128
#define SEQ      20
#define HL       128
#define G4       512
#define BWIN     (N_GRAPHS - SEQ + 1)  // 181
#define NPART    512
#define EPB      (N_EDGES_/NPART)      // 3125
#define SLOTS    48
#define CAP      9216

typedef __attribute__((ext_vector_type(8))) short short8;
typedef __attribute__((ext_vector_type(4))) float float4v;
typedef __attribute__((ext_vector_type(2))) _Float16 half2v;

__device__ __forceinline__ float sigmoidf_(float v){ return 1.0f/(1.0f+expf(-v)); }

__device__ __forceinline__ unsigned short f2bf(float f) {
  unsigned int u = __float_as_uint(f);
  u += 0x7fffu + ((u >> 16) & 1u);
  return (unsigned short)(u >> 16);
}

__device__ __forceinline__ float h2dot(half2v a, half2v b, float c) {
#if __has_builtin(__builtin_amdgcn_fdot2)
  return __builtin_amdgcn_fdot2(a, b, c, false);
#else
  return c + (float)a.x*(float)b.x + (float)a.y*(float)b.y;
#endif
}

// K1: edge partition + w_hh fp32->fp16 conversion on blocks 0..31.
__global__ __launch_bounds__(256) void k_part(const int* __restrict__ src,
                                              const int* __restrict__ dst,
                                              const float* __restrict__ w_hh,
                                              int* __restrict__ gcount,
                                              int* __restrict__ part,
                                              int4* __restrict__ whh16) {
  __shared__ int cnt[N_GRAPHS];
  __shared__ int base[N_GRAPHS];
  __shared__ int buf[N_GRAPHS][SLOTS];   // 38.4 KB
  int b = blockIdx.x, t = threadIdx.x;
  if (b < 32) {                          // whh16[i], i = k4*512 + r
    int i = b*256 + t;
    int k4 = i >> 9, r = i & 511;
    const float4* wp = (const float4*)(w_hh + (size_t)r*HL + k4*8);
    float4 w0 = wp[0], w1 = wp[1];
    half2v p0 = {(_Float16)w0.x, (_Float16)w0.y};
    half2v p1 = {(_Float16)w0.z, (_Float16)w0.w};
    half2v p2 = {(_Float16)w1.x, (_Float16)w1.y};
    half2v p3 = {(_Float16)w1.z, (_Float16)w1.w};
    int4 pk;
    pk.x = __builtin_bit_cast(int, p0); pk.y = __builtin_bit_cast(int, p1);
    pk.z = __builtin_bit_cast(int, p2); pk.w = __builtin_bit_cast(int, p3);
    whh16[i] = pk;
  }
  for (int g = t; g < N_GRAPHS; g += 256) cnt[g] = 0;
  __syncthreads();
  int e0 = b*EPB;
  for (int i = t; i < EPB; i += 256) {
    int s = src[e0+i], d = dst[e0+i];
    int g = s / NPG;
    int pk = ((s - g*NPG) << 9) | (d - g*NPG);
    int pos = atomicAdd(&cnt[g], 1);
    if (pos < SLOTS) buf[g][pos] = pk;
    else { int gp = atomicAdd(&gcount[g], 1); part[g*CAP + gp] = pk; }
  }
  __syncthreads();
  if (t < N_GRAPHS) base[t] = atomicAdd(&gcount[t], min(cnt[t], SLOTS));
  __syncthreads();
  int w = t >> 6, lane = t & 63;
  for (int g = w; g < N_GRAPHS; g += 4) {
    int n = min(cnt[g], SLOTS);
    if (lane < n) part[g*CAP + base[g] + lane] = buf[g][lane];
  }
}

// K2: fully fused per-graph pipeline: counting sort (LDS-resident output) ->
// xprep -> aggregation -> MFMA GEMM + ReLU + mean pool -> input projection.
// One block per graph, 152.7 KB LDS, 1 block/CU. All phases block-local
// (no grid sync — the round-2 trap was grid-synced fusion, not this).
// sorted/e_end/e_deg/so never touch HBM anymore. Edge list is read from
// global twice (histogram + scatter), trading 6.4 MB of coalesced BW for
// 37 KB of LDS. w_gcn prefetched to registers so staging latency hides
// under the histogram.
__global__ __launch_bounds__(512, 1) void k_graph(
    const int* __restrict__ gcount, const int* __restrict__ part,
    const float* __restrict__ x,
    const float* __restrict__ w_gcn, const float* __restrict__ b_gcn,
    const float* __restrict__ w_ih,  const float* __restrict__ b_ih,
    float* __restrict__ proj) {
  __shared__ int indeg[512];                    // -> pS overlay after agg
  __shared__ int outdeg[512];                   // -> pS overlay after agg
  __shared__ int off[512];                      // excl start -> incl end; -> hgS
  __shared__ float soS[512];
  __shared__ int wsum[8];
  __shared__ float fpS[2];                      // (unused pad)
  __shared__ unsigned short sorted[CAP];        // 18.4 KB; -> wLds overlay
  __shared__ __align__(16) int4 xs[4008];       // 64.1 KB (500 rows + zero row)
  __shared__ __align__(16) int4 hpre[4096];     // 64 KB swizzled
  int g = blockIdx.x, t = threadIdx.x;
  int lane = t & 63, w = t >> 6;

  // early register prefetch of w_gcn (4 float4/thread, latency hidden)
  float4 wg[4];
  #pragma unroll
  for (int q = 0; q < 4; ++q) wg[q] = ((const float4*)w_gcn)[t + q*512];

  // ---- histogram ----
  indeg[t] = 0; outdeg[t] = 0;
  __syncthreads();
  int nseg = gcount[g], seg0 = g*CAP;
  for (int e = t; e < nseg; e += 512) {
    int p = part[seg0 + e];
    atomicAdd(&indeg[p & 511], 1);
    atomicAdd(&outdeg[p >> 9], 1);
  }
  __syncthreads();
  // ---- exclusive scan over 512 in-degree slots ----
  int v = indeg[t], sc = v;
  #pragma unroll
  for (int o = 1; o < 64; o <<= 1) { int nn = __shfl_up(sc, o); if (lane >= o) sc += nn; }
  if (lane == 63) wsum[w] = sc;
  __syncthreads();
  int woff = 0;
  #pragma unroll
  for (int i = 0; i < 8; ++i) woff += (i < w) ? wsum[i] : 0;
  off[t] = woff + sc - v;
  soS[t] = rsqrtf((float)max(outdeg[t], 1));
  __syncthreads();
  // ---- xprep: x * so -> bf16 rows in LDS ----
  const float4* xg = ((const float4*)x) + (size_t)g*8000;
  ushort4* xd = (ushort4*)xs;
  for (int i = t; i < 8000; i += 512) {
    float4 vv = xg[i];
    float s2 = soS[i >> 4];
    ushort4 u;
    u.x = f2bf(vv.x*s2); u.y = f2bf(vv.y*s2); u.z = f2bf(vv.z*s2); u.w = f2bf(vv.w*s2);
    xd[i] = u;
  }
  if (t < 16) xd[8000 + t] = make_ushort4(0,0,0,0);
  // ---- scatter (re-read part, coalesced) ----
  for (int e = t; e < nseg; e += 512) {
    int p = part[seg0 + e];
    int pos = atomicAdd(&off[p & 511], 1);      // off becomes inclusive end
    sorted[pos] = (unsigned short)(p >> 9);
  }
  __syncthreads();
  // ---- aggregation: 64 groups x 8 lanes, 8 nodes/group ----
  int g8 = lane >> 3, fl = lane & 7;
  int G = w*8 + g8;
  for (int sI = 0; sI < 8; ++sI) {
    int nl = sI*64 + G;
    int4 outv = make_int4(0,0,0,0);
    if (nl < NPG) {
      int end = off[nl], dgr = indeg[nl], st = end - dgr;
      float aHi[4] = {0.f,0.f,0.f,0.f};
      float aLo[4] = {0.f,0.f,0.f,0.f};
      int ev = (fl < dgr) ? (int)sorted[st + fl] : 500;
      for (int c0 = 0; c0 < dgr; c0 += 8) {
        int nc = c0 + 8;
        int evn = (nc + fl < dgr) ? (int)sorted[st + nc + fl] : 500;
        #pragma unroll
        for (int j = 0; j < 8; ++j) {
          int se = __shfl(ev, (g8 << 3) + j);
          int4 vv = xs[(se << 3) + fl];
          aHi[0] += __uint_as_float((unsigned)vv.x & 0xffff0000u);
          aLo[0] += __uint_as_float((unsigned)vv.x << 16);
          aHi[1] += __uint_as_float((unsigned)vv.y & 0xffff0000u);
          aLo[1] += __uint_as_float((unsigned)vv.y << 16);
          aHi[2] += __uint_as_float((unsigned)vv.z & 0xffff0000u);
          aLo[2] += __uint_as_float((unsigned)vv.z << 16);
          aHi[3] += __uint_as_float((unsigned)vv.w & 0xffff0000u);
          aLo[3] += __uint_as_float((unsigned)vv.w << 16);
        }
        ev = evn;
      }
      float sn = rsqrtf((float)max(dgr, 1));
      outv.x = (int)(((unsigned)f2bf(aLo[0]*sn)) | ((unsigned)f2bf(aHi[0]*sn) << 16));
      outv.y = (int)(((unsigned)f2bf(aLo[1]*sn)) | ((unsigned)f2bf(aHi[1]*sn) << 16));
      outv.z = (int)(((unsigned)f2bf(aLo[2]*sn)) | ((unsigned)f2bf(aHi[2]*sn) << 16));
      outv.w = (int)(((unsigned)f2bf(aLo[3]*sn)) | ((unsigned)f2bf(aHi[3]*sn) << 16));
    }
    hpre[(nl << 3) + (fl ^ (nl & 7))] = outv;   // swizzled, conflict-free
  }
  __syncthreads();
  // ---- stage w_gcn from registers into wLds (overlays sorted, now dead) ----
  unsigned short* wLds = (unsigned short*)sorted;
  #pragma unroll
  for (int q = 0; q < 4; ++q) {
    int i = t + q*512;
    int k = i >> 5, c4 = (i & 31) << 2;
    int h = k >> 5, j = k & 7, lhi = ((k >> 3) & 3) << 4;
    float vvv[4] = {wg[q].x, wg[q].y, wg[q].z, wg[q].w};
    #pragma unroll
    for (int u = 0; u < 4; ++u) {
      int n = c4 + u;
      int idx = ((n >> 4)*2 + h)*64 + lhi + (n & 15);
      wLds[idx*8 + j] = f2bf(vvv[u]);
    }
  }
  __syncthreads();
  // ---- MFMA GEMM + ReLU + mean pool ----
  float* pS  = (float*)indeg;                   // 4 KB overlay (indeg+outdeg dead)
  float* hgS = (float*)off;                     // overlay (off dead after agg)
  int quad = lane >> 4, l15 = lane & 15;
  float bcol[8];
  #pragma unroll
  for (int nt = 0; nt < 8; ++nt) bcol[nt] = b_gcn[nt*16 + l15];
  float psum[8] = {0.f,0.f,0.f,0.f,0.f,0.f,0.f,0.f};
  for (int i = 0; i < 4; ++i) {
    int row0 = (w + 8*i) << 4;
    int r = row0 + l15;
    int4 a0i = hpre[(r << 3) + (quad ^ (r & 7))];
    int4 a1i = hpre[(r << 3) + ((quad + 4) ^ (r & 7))];
    short8 a0 = *(const short8*)&a0i;
    short8 a1 = *(const short8*)&a1i;
    #pragma unroll
    for (int nt = 0; nt < 8; ++nt) {
      short8 b0 = *((const short8*)&wLds[((nt*2+0)*64 + lane)*8]);
      short8 b1 = *((const short8*)&wLds[((nt*2+1)*64 + lane)*8]);
      float4v acc = {0.f, 0.f, 0.f, 0.f};
      acc = __builtin_amdgcn_mfma_f32_16x16x32_bf16(a0, b0, acc, 0, 0, 0);
      acc = __builtin_amdgcn_mfma_f32_16x16x32_bf16(a1, b1, acc, 0, 0, 0);
      #pragma unroll
      for (int r4 = 0; r4 < 4; ++r4) {
        int node = row0 + quad*4 + r4;
        float vvv = acc[r4] + bcol[nt];
        psum[nt] += (node < NPG) ? fmaxf(vvv, 0.f) : 0.f;
      }
    }
  }
  #pragma unroll
  for (int nt = 0; nt < 8; ++nt) {
    float vvv = psum[nt];
    vvv += __shfl_xor(vvv, 16);
    vvv += __shfl_xor(vvv, 32);
    if (lane < 16) pS[w*DG + nt*16 + lane] = vvv;
  }
  __syncthreads();
  if (t < DG) {
    float sum = 0.f;
    #pragma unroll
    for (int w8 = 0; w8 < 8; ++w8) sum += pS[w8*DG + t];
    hgS[t] = sum * (1.0f/NPG);
  }
  __syncthreads();
  // ---- fused input projection: thread t -> row t of w_ih ----
  const float4* wr = (const float4*)(w_ih + (size_t)t*HL);
  const float4* hv = (const float4*)hgS;
  float acc = b_ih[t];
  #pragma unroll
  for (int k4 = 0; k4 < 32; ++k4) {
    float4 w4 = wr[k4]; float4 h4 = hv[k4];
    acc += w4.x*h4.x + w4.y*h4.y + w4.z*h4.z + w4.w*h4.w;
  }
  proj[(size_t)g*G4 + t] = acc;
  (void)fpS;
}

// K3: LSTM. w_hh fp16 in registers; h broadcast from LDS. Round-change:
// gate nonlinearities spread over 128 threads (one h-element each, 5
// transcendentals vs 10), h packed to fp16 via lane-pair shfl.
__global__ __launch_bounds__(512) void k_lstm(const float* __restrict__ proj,
    const int4* __restrict__ whh16, const float* __restrict__ b_hh,
    const float* __restrict__ w_fc, const float* __restrict__ b_fc,
    float* __restrict__ out) {
  __shared__ float gS[G4];
  __shared__ __align__(16) int4 hPi[16];  // 128 fp16 packed h state
  __shared__ float fcS[2];
  int b = blockIdx.x, t = threadIdx.x;
  int4 W[16];
  #pragma unroll
  for (int k4 = 0; k4 < 16; ++k4) W[k4] = whh16[(k4 << 9) + t];   // coalesced
  if (t < 16) hPi[t] = make_int4(0,0,0,0);
  float bh = b_hh[t];
  float c = 0.f;
  __syncthreads();
  for (int l = 0; l < SEQ; ++l) {
    float a0 = proj[(size_t)(b+l)*G4 + t] + bh;
    float a1 = 0.f, a2 = 0.f, a3 = 0.f;
    #pragma unroll
    for (int k4 = 0; k4 < 16; k4 += 4) {
      int4 hv0 = hPi[k4+0]; int4 hv1 = hPi[k4+1];
      int4 hv2 = hPi[k4+2]; int4 hv3 = hPi[k4+3];
      a0 = h2dot(__builtin_bit_cast(half2v, W[k4+0].x), __builtin_bit_cast(half2v, hv0.x), a0);
      a0 = h2dot(__builtin_bit_cast(half2v, W[k4+0].y), __builtin_bit_cast(half2v, hv0.y), a0);
      a0 = h2dot(__builtin_bit_cast(half2v, W[k4+0].z), __builtin_bit_cast(half2v, hv0.z), a0);
      a0 = h2dot(__builtin_bit_cast(half2v, W[k4+0].w), __builtin_bit_cast(half2v, hv0.w), a0);
      a1 = h2dot(__builtin_bit_cast(half2v, W[k4+1].x), __builtin_bit_cast(half2v, hv1.x), a1);
      a1 = h2dot(__builtin_bit_cast(half2v, W[k4+1].y), __builtin_bit_cast(half2v, hv1.y), a1);
      a1 = h2dot(__builtin_bit_cast(half2v, W[k4+1].z), __builtin_bit_cast(half2v, hv1.z), a1);
      a1 = h2dot(__builtin_bit_cast(half2v, W[k4+1].w), __builtin_bit_cast(half2v, hv1.w), a1);
      a2 = h2dot(__builtin_bit_cast(half2v, W[k4+2].x), __builtin_bit_cast(half2v, hv2.x), a2);
      a2 = h2dot(__builtin_bit_cast(half2v, W[k4+2].y), __builtin_bit_cast(half2v, hv2.y), a2);
      a2 = h2dot(__builtin_bit_cast(half2v, W[k4+2].z), __builtin_bit_cast(half2v, hv2.z), a2);
      a2 = h2dot(__builtin_bit_cast(half2v, W[k4+2].w), __builtin_bit_cast(half2v, hv2.w), a2);
      a3 = h2dot(__builtin_bit_cast(half2v, W[k4+3].x), __builtin_bit_cast(half2v, hv3.x), a3);
      a3 = h2dot(__builtin_bit_cast(half2v, W[k4+3].y), __builtin_bit_cast(half2v, hv3.y), a3);
      a3 = h2dot(__builtin_bit_cast(half2v, W[k4+3].z), __builtin_bit_cast(half2v, hv3.z), a3);
      a3 = h2dot(__builtin_bit_cast(half2v, W[k4+3].w), __builtin_bit_cast(half2v, hv3.w), a3);
    }
    gS[t] = (a0 + a1) + (a2 + a3);
    __syncthreads();
    if (t < 128) {
      float iv = sigmoidf_(gS[t]);
      float fv = sigmoidf_(gS[HL + t]);
      float gv = tanhf(gS[2*HL + t]);
      float ov = sigmoidf_(gS[3*HL + t]);
      c = fv*c + iv*gv;
      float h = ov * tanhf(c);
      float hp2 = __shfl_xor(h, 1);           // partner within wave
      if (!(t & 1)) {
        half2v hp = {(_Float16)h, (_Float16)hp2};
        ((int*)hPi)[t >> 1] = __builtin_bit_cast(int, hp);
      }
      if (l == SEQ-1) {
        float s = h * w_fc[t];
        #pragma unroll
        for (int o = 32; o > 0; o >>= 1) s += __shfl_down(s, o);
        if ((t & 63) == 0) fcS[t >> 6] = s;
      }
    }
    __syncthreads();
  }
  if (t == 0) out[b] = fcS[0] + fcS[1] + b_fc[0];
}

extern "C" void kernel_launch(void* const* d_in, const int* in_sizes, int n_in,
                              void* d_out, int out_size, void* d_ws, size_t ws_size,
                              hipStream_t stream) {
  const float* x     = (const float*)d_in[0];
  const int*   src   = (const int*)d_in[1];
  const int*   dst   = (const int*)d_in[2];
  const float* w_gcn = (const float*)d_in[4];
  const float* b_gcn = (const float*)d_in[5];
  const float* w_ih  = (const float*)d_in[6];
  const float* w_hh  = (const float*)d_in[7];
  const float* b_ih  = (const float*)d_in[8];
  const float* b_hh  = (const float*)d_in[9];
  const float* w_fc  = (const float*)d_in[10];
  const float* b_fc  = (const float*)d_in[11];
  float* out = (float*)d_out;

  char* ws = (char*)d_ws;
  size_t off = 0;
  auto alloc = [&](size_t bytes) -> void* {
    void* p = ws + off; off += (bytes + 255) & ~(size_t)255; return p;
  };
  int* gcount  = (int*)alloc((size_t)N_GRAPHS*4);
  int* part    = (int*)alloc((size_t)N_GRAPHS*CAP*4);
  int4* whh16  = (int4*)alloc((size_t)8192*16);
  float* proj  = (float*)alloc((size_t)N_GRAPHS*G4*4);
  (void)ws_size; (void)in_sizes; (void)n_in; (void)out_size;

  hipMemsetAsync(gcount, 0, (size_t)N_GRAPHS*4, stream);
  k_part<<<NPART, 256, 0, stream>>>(src, dst, w_hh, gcount, part, whh16);
  k_graph<<<N_GRAPHS, 512, 0, stream>>>(gcount, part, x, w_gcn, b_gcn, w_ih, b_ih, proj);
  k_lstm<<<BWIN, 512, 0, stream>>>(proj, whh16, b_hh, w_fc, b_fc, out);
}

// Round 5
// 171.388 us; speedup vs baseline: 1.5658x; 1.0654x over previous
//
#include <hip/hip_runtime.h>
#include <hip/hip_bf16.h>

#define N_GRAPHS 200
#define NPG      500
#define NPGP     512
#define N_NODES_ 100000
#define N_EDGES_ 1600000
#define DIN      64
#define DG       128
#define SEQ      20
#define HL       128
#define G4       512
#define BWIN     (N_GRAPHS - SEQ + 1)  // 181
#define NPART    512
#define EPB      (N_EDGES_/NPART)      // 3125
#define SLOTS    48
#define CAP      9216

typedef __attribute__((ext_vector_type(8))) short short8;
typedef __attribute__((ext_vector_type(4))) float float4v;
typedef __attribute__((ext_vector_type(2))) _Float16 half2v;

__device__ __forceinline__ float sigmoidf_(float v){ return 1.0f/(1.0f+expf(-v)); }

__device__ __forceinline__ unsigned short f2bf(float f) {
  unsigned int u = __float_as_uint(f);
  u += 0x7fffu + ((u >> 16) & 1u);
  return (unsigned short)(u >> 16);
}

__device__ __forceinline__ float h2dot(half2v a, half2v b, float c) {
#if __has_builtin(__builtin_amdgcn_fdot2)
  return __builtin_amdgcn_fdot2(a, b, c, false);
#else
  return c + (float)a.x*(float)b.x + (float)a.y*(float)b.y;
#endif
}

// K1: edge partition + w_hh fp32->fp16 conversion on blocks 0..31.
__global__ __launch_bounds__(256) void k_part(const int* __restrict__ src,
                                              const int* __restrict__ dst,
                                              const float* __restrict__ w_hh,
                                              int* __restrict__ gcount,
                                              int* __restrict__ part,
                                              int4* __restrict__ whh16) {
  __shared__ int cnt[N_GRAPHS];
  __shared__ int base[N_GRAPHS];
  __shared__ int buf[N_GRAPHS][SLOTS];   // 38.4 KB
  int b = blockIdx.x, t = threadIdx.x;
  if (b < 32) {                          // whh16[i], i = k4*512 + r
    int i = b*256 + t;
    int k4 = i >> 9, r = i & 511;
    const float4* wp = (const float4*)(w_hh + (size_t)r*HL + k4*8);
    float4 w0 = wp[0], w1 = wp[1];
    half2v p0 = {(_Float16)w0.x, (_Float16)w0.y};
    half2v p1 = {(_Float16)w0.z, (_Float16)w0.w};
    half2v p2 = {(_Float16)w1.x, (_Float16)w1.y};
    half2v p3 = {(_Float16)w1.z, (_Float16)w1.w};
    int4 pk;
    pk.x = __builtin_bit_cast(int, p0); pk.y = __builtin_bit_cast(int, p1);
    pk.z = __builtin_bit_cast(int, p2); pk.w = __builtin_bit_cast(int, p3);
    whh16[i] = pk;
  }
  for (int g = t; g < N_GRAPHS; g += 256) cnt[g] = 0;
  __syncthreads();
  int e0 = b*EPB;
  for (int i = t; i < EPB; i += 256) {
    int s = src[e0+i], d = dst[e0+i];
    int g = s / NPG;
    int pk = ((s - g*NPG) << 9) | (d - g*NPG);
    int pos = atomicAdd(&cnt[g], 1);
    if (pos < SLOTS) buf[g][pos] = pk;
    else { int gp = atomicAdd(&gcount[g], 1); part[g*CAP + gp] = pk; }
  }
  __syncthreads();
  if (t < N_GRAPHS) base[t] = atomicAdd(&gcount[t], min(cnt[t], SLOTS));
  __syncthreads();
  int w = t >> 6, lane = t & 63;
  for (int g = w; g < N_GRAPHS; g += 4) {
    int n = min(cnt[g], SLOTS);
    if (lane < n) part[g*CAP + base[g] + lane] = buf[g][lane];
  }
}

// K2: fused per-graph pipeline at 1024 threads (16 waves/CU — round-4 ran 8
// waves and was latency-bound at 48.5 µs with all pipes <25% busy).
// Round-changes: (a) 1024-thread block doubles latency-hiding waves and
// halves per-phase trip counts; (b) part slice cached in REGISTERS during
// histogram -> scatter re-reads regs, killing the 2nd global pass and its
// latency chain; (c) proj row split across a thread pair (halves load chain);
// (d) agg: 128 groups x 4 nodes (better imbalance averaging).
__global__ __launch_bounds__(1024) void k_graph(
    const int* __restrict__ gcount, const int* __restrict__ part,
    const float* __restrict__ x,
    const float* __restrict__ w_gcn, const float* __restrict__ b_gcn,
    const float* __restrict__ w_ih,  const float* __restrict__ b_ih,
    float* __restrict__ proj) {
  __shared__ int meta[2048];                    // indeg|outdeg|off|soS; -> pS
  __shared__ int wsum[8];
  __shared__ __align__(16) float hgS[DG];
  __shared__ unsigned short sorted[CAP];        // 18.4 KB; -> wLds overlay
  __shared__ __align__(16) int4 xs[4008];       // 64.1 KB (500 rows + zero row)
  __shared__ __align__(16) int4 hpre[4096];     // 64 KB swizzled
  int* indeg  = meta;
  int* outdeg = meta + 512;
  int* off    = meta + 1024;
  float* soS  = (float*)(meta + 1536);
  int g = blockIdx.x, t = threadIdx.x;
  int lane = t & 63, w = t >> 6;                // w: 0..15

  // early register prefetch of w_gcn (2 float4/thread)
  float4 wg[2];
  #pragma unroll
  for (int q = 0; q < 2; ++q) wg[q] = ((const float4*)w_gcn)[t + q*1024];

  // ---- histogram (part slice cached in registers) ----
  meta[t] = 0; meta[t + 1024] = 0;              // zero indeg+outdeg
  __syncthreads();
  int nseg = gcount[g], seg0 = g*CAP;
  int pr[9];
  #pragma unroll
  for (int q = 0; q < 9; ++q) {
    int e = t + q*1024;
    pr[q] = (e < nseg) ? part[seg0 + e] : -1;
  }
  #pragma unroll
  for (int q = 0; q < 9; ++q) {
    int p = pr[q];
    if (p >= 0) {
      atomicAdd(&indeg[p & 511], 1);
      atomicAdd(&outdeg[p >> 9], 1);
    }
  }
  __syncthreads();
  // ---- exclusive scan over 512 in-degree slots (first 8 waves) ----
  if (t < 512) {
    int v = indeg[t], sc = v;
    #pragma unroll
    for (int o = 1; o < 64; o <<= 1) { int nn = __shfl_up(sc, o); if (lane >= o) sc += nn; }
    if (lane == 63) wsum[t >> 6] = sc;
    __syncthreads();
    int woff = 0;
    #pragma unroll
    for (int i = 0; i < 8; ++i) woff += (i < (t >> 6)) ? wsum[i] : 0;
    off[t] = woff + sc - v;
    soS[t] = rsqrtf((float)max(outdeg[t], 1));
  } else {
    __syncthreads();
  }
  __syncthreads();
  // ---- xprep: x * so -> bf16 rows in LDS ----
  const float4* xg = ((const float4*)x) + (size_t)g*8000;
  ushort4* xd = (ushort4*)xs;
  for (int i = t; i < 8000; i += 1024) {
    float4 vv = xg[i];
    float s2 = soS[i >> 4];
    ushort4 u;
    u.x = f2bf(vv.x*s2); u.y = f2bf(vv.y*s2); u.z = f2bf(vv.z*s2); u.w = f2bf(vv.w*s2);
    xd[i] = u;
  }
  if (t < 16) xd[8000 + t] = make_ushort4(0,0,0,0);
  // ---- scatter (from registers) ----
  #pragma unroll
  for (int q = 0; q < 9; ++q) {
    int p = pr[q];
    if (p >= 0) {
      int pos = atomicAdd(&off[p & 511], 1);    // off becomes inclusive end
      sorted[pos] = (unsigned short)(p >> 9);
    }
  }
  __syncthreads();
  // ---- aggregation: 128 groups x 8 lanes, 4 nodes/group ----
  int g8 = lane >> 3, fl = lane & 7;
  int G = w*8 + g8;                             // 0..127
  for (int sI = 0; sI < 4; ++sI) {
    int nl = sI*128 + G;
    int4 outv = make_int4(0,0,0,0);
    if (nl < NPG) {
      int end = off[nl], dgr = indeg[nl], st = end - dgr;
      float aHi[4] = {0.f,0.f,0.f,0.f};
      float aLo[4] = {0.f,0.f,0.f,0.f};
      int ev = (fl < dgr) ? (int)sorted[st + fl] : 500;
      for (int c0 = 0; c0 < dgr; c0 += 8) {
        int nc = c0 + 8;
        int evn = (nc + fl < dgr) ? (int)sorted[st + nc + fl] : 500;
        #pragma unroll
        for (int j = 0; j < 8; ++j) {
          int se = __shfl(ev, (g8 << 3) + j);
          int4 vv = xs[(se << 3) + fl];
          aHi[0] += __uint_as_float((unsigned)vv.x & 0xffff0000u);
          aLo[0] += __uint_as_float((unsigned)vv.x << 16);
          aHi[1] += __uint_as_float((unsigned)vv.y & 0xffff0000u);
          aLo[1] += __uint_as_float((unsigned)vv.y << 16);
          aHi[2] += __uint_as_float((unsigned)vv.z & 0xffff0000u);
          aLo[2] += __uint_as_float((unsigned)vv.z << 16);
          aHi[3] += __uint_as_float((unsigned)vv.w & 0xffff0000u);
          aLo[3] += __uint_as_float((unsigned)vv.w << 16);
        }
        ev = evn;
      }
      float sn = rsqrtf((float)max(dgr, 1));
      outv.x = (int)(((unsigned)f2bf(aLo[0]*sn)) | ((unsigned)f2bf(aHi[0]*sn) << 16));
      outv.y = (int)(((unsigned)f2bf(aLo[1]*sn)) | ((unsigned)f2bf(aHi[1]*sn) << 16));
      outv.z = (int)(((unsigned)f2bf(aLo[2]*sn)) | ((unsigned)f2bf(aHi[2]*sn) << 16));
      outv.w = (int)(((unsigned)f2bf(aLo[3]*sn)) | ((unsigned)f2bf(aHi[3]*sn) << 16));
    }
    hpre[(nl << 3) + (fl ^ (nl & 7))] = outv;   // swizzled, conflict-free
  }
  __syncthreads();
  // ---- stage w_gcn from registers into wLds (overlays sorted, now dead) ----
  unsigned short* wLds = (unsigned short*)sorted;
  #pragma unroll
  for (int q = 0; q < 2; ++q) {
    int i = t + q*1024;
    int k = i >> 5, c4 = (i & 31) << 2;
    int h = k >> 5, j = k & 7, lhi = ((k >> 3) & 3) << 4;
    float vvv[4] = {wg[q].x, wg[q].y, wg[q].z, wg[q].w};
    #pragma unroll
    for (int u = 0; u < 4; ++u) {
      int n = c4 + u;
      int idx = ((n >> 4)*2 + h)*64 + lhi + (n & 15);
      wLds[idx*8 + j] = f2bf(vvv[u]);
    }
  }
  __syncthreads();
  // ---- MFMA GEMM + ReLU + mean pool ----
  float* pS = (float*)meta;                     // 8 KB overlay (meta dead)
  int quad = lane >> 4, l15 = lane & 15;
  float bcol[8];
  #pragma unroll
  for (int nt = 0; nt < 8; ++nt) bcol[nt] = b_gcn[nt*16 + l15];
  float psum[8] = {0.f,0.f,0.f,0.f,0.f,0.f,0.f,0.f};
  #pragma unroll
  for (int i = 0; i < 2; ++i) {
    int row0 = (w + 16*i) << 4;
    int r = row0 + l15;
    int4 a0i = hpre[(r << 3) + (quad ^ (r & 7))];
    int4 a1i = hpre[(r << 3) + ((quad + 4) ^ (r & 7))];
    short8 a0 = *(const short8*)&a0i;
    short8 a1 = *(const short8*)&a1i;
    #pragma unroll
    for (int nt = 0; nt < 8; ++nt) {
      short8 b0 = *((const short8*)&wLds[((nt*2+0)*64 + lane)*8]);
      short8 b1 = *((const short8*)&wLds[((nt*2+1)*64 + lane)*8]);
      float4v acc = {0.f, 0.f, 0.f, 0.f};
      acc = __builtin_amdgcn_mfma_f32_16x16x32_bf16(a0, b0, acc, 0, 0, 0);
      acc = __builtin_amdgcn_mfma_f32_16x16x32_bf16(a1, b1, acc, 0, 0, 0);
      #pragma unroll
      for (int r4 = 0; r4 < 4; ++r4) {
        int node = row0 + quad*4 + r4;
        float vvv = acc[r4] + bcol[nt];
        psum[nt] += (node < NPG) ? fmaxf(vvv, 0.f) : 0.f;
      }
    }
  }
  #pragma unroll
  for (int nt = 0; nt < 8; ++nt) {
    float vvv = psum[nt];
    vvv += __shfl_xor(vvv, 16);
    vvv += __shfl_xor(vvv, 32);
    if (lane < 16) pS[w*DG + nt*16 + lane] = vvv;
  }
  __syncthreads();
  if (t < DG) {
    float sum = 0.f;
    #pragma unroll
    for (int w16 = 0; w16 < 16; ++w16) sum += pS[w16*DG + t];
    hgS[t] = sum * (1.0f/NPG);
  }
  __syncthreads();
  // ---- fused input projection: thread pair -> row t>>1 of w_ih ----
  {
    int r = t >> 1, half = t & 1;
    const float4* wr = (const float4*)(w_ih + (size_t)r*HL) + half*16;
    const float4* hv = (const float4*)hgS + half*16;
    float acc = half ? 0.f : b_ih[r];
    #pragma unroll
    for (int k4 = 0; k4 < 16; ++k4) {
      float4 w4 = wr[k4]; float4 h4 = hv[k4];
      acc += w4.x*h4.x + w4.y*h4.y + w4.z*h4.z + w4.w*h4.w;
    }
    acc += __shfl_xor(acc, 1);
    if (!half) proj[(size_t)g*G4 + r] = acc;
  }
}

// K3: LSTM. w_hh fp16 in registers; h broadcast from LDS; gate
// nonlinearities over 128 threads; h packed via lane-pair shfl.
__global__ __launch_bounds__(512) void k_lstm(const float* __restrict__ proj,
    const int4* __restrict__ whh16, const float* __restrict__ b_hh,
    const float* __restrict__ w_fc, const float* __restrict__ b_fc,
    float* __restrict__ out) {
  __shared__ float gS[G4];
  __shared__ __align__(16) int4 hPi[16];  // 128 fp16 packed h state
  __shared__ float fcS[2];
  int b = blockIdx.x, t = threadIdx.x;
  int4 W[16];
  #pragma unroll
  for (int k4 = 0; k4 < 16; ++k4) W[k4] = whh16[(k4 << 9) + t];   // coalesced
  if (t < 16) hPi[t] = make_int4(0,0,0,0);
  float bh = b_hh[t];
  float c = 0.f;
  __syncthreads();
  for (int l = 0; l < SEQ; ++l) {
    float a0 = proj[(size_t)(b+l)*G4 + t] + bh;
    float a1 = 0.f, a2 = 0.f, a3 = 0.f;
    #pragma unroll
    for (int k4 = 0; k4 < 16; k4 += 4) {
      int4 hv0 = hPi[k4+0]; int4 hv1 = hPi[k4+1];
      int4 hv2 = hPi[k4+2]; int4 hv3 = hPi[k4+3];
      a0 = h2dot(__builtin_bit_cast(half2v, W[k4+0].x), __builtin_bit_cast(half2v, hv0.x), a0);
      a0 = h2dot(__builtin_bit_cast(half2v, W[k4+0].y), __builtin_bit_cast(half2v, hv0.y), a0);
      a0 = h2dot(__builtin_bit_cast(half2v, W[k4+0].z), __builtin_bit_cast(half2v, hv0.z), a0);
      a0 = h2dot(__builtin_bit_cast(half2v, W[k4+0].w), __builtin_bit_cast(half2v, hv0.w), a0);
      a1 = h2dot(__builtin_bit_cast(half2v, W[k4+1].x), __builtin_bit_cast(half2v, hv1.x), a1);
      a1 = h2dot(__builtin_bit_cast(half2v, W[k4+1].y), __builtin_bit_cast(half2v, hv1.y), a1);
      a1 = h2dot(__builtin_bit_cast(half2v, W[k4+1].z), __builtin_bit_cast(half2v, hv1.z), a1);
      a1 = h2dot(__builtin_bit_cast(half2v, W[k4+1].w), __builtin_bit_cast(half2v, hv1.w), a1);
      a2 = h2dot(__builtin_bit_cast(half2v, W[k4+2].x), __builtin_bit_cast(half2v, hv2.x), a2);
      a2 = h2dot(__builtin_bit_cast(half2v, W[k4+2].y), __builtin_bit_cast(half2v, hv2.y), a2);
      a2 = h2dot(__builtin_bit_cast(half2v, W[k4+2].z), __builtin_bit_cast(half2v, hv2.z), a2);
      a2 = h2dot(__builtin_bit_cast(half2v, W[k4+2].w), __builtin_bit_cast(half2v, hv2.w), a2);
      a3 = h2dot(__builtin_bit_cast(half2v, W[k4+3].x), __builtin_bit_cast(half2v, hv3.x), a3);
      a3 = h2dot(__builtin_bit_cast(half2v, W[k4+3].y), __builtin_bit_cast(half2v, hv3.y), a3);
      a3 = h2dot(__builtin_bit_cast(half2v, W[k4+3].z), __builtin_bit_cast(half2v, hv3.z), a3);
      a3 = h2dot(__builtin_bit_cast(half2v, W[k4+3].w), __builtin_bit_cast(half2v, hv3.w), a3);
    }
    gS[t] = (a0 + a1) + (a2 + a3);
    __syncthreads();
    if (t < 128) {
      float iv = sigmoidf_(gS[t]);
      float fv = sigmoidf_(gS[HL + t]);
      float gv = tanhf(gS[2*HL + t]);
      float ov = sigmoidf_(gS[3*HL + t]);
      c = fv*c + iv*gv;
      float h = ov * tanhf(c);
      float hp2 = __shfl_xor(h, 1);           // partner within wave
      if (!(t & 1)) {
        half2v hp = {(_Float16)h, (_Float16)hp2};
        ((int*)hPi)[t >> 1] = __builtin_bit_cast(int, hp);
      }
      if (l == SEQ-1) {
        float s = h * w_fc[t];
        #pragma unroll
        for (int o = 32; o > 0; o >>= 1) s += __shfl_down(s, o);
        if ((t & 63) == 0) fcS[t >> 6] = s;
      }
    }
    __syncthreads();
  }
  if (t == 0) out[b] = fcS[0] + fcS[1] + b_fc[0];
}

extern "C" void kernel_launch(void* const* d_in, const int* in_sizes, int n_in,
                              void* d_out, int out_size, void* d_ws, size_t ws_size,
                              hipStream_t stream) {
  const float* x     = (const float*)d_in[0];
  const int*   src   = (const int*)d_in[1];
  const int*   dst   = (const int*)d_in[2];
  const float* w_gcn = (const float*)d_in[4];
  const float* b_gcn = (const float*)d_in[5];
  const float* w_ih  = (const float*)d_in[6];
  const float* w_hh  = (const float*)d_in[7];
  const float* b_ih  = (const float*)d_in[8];
  const float* b_hh  = (const float*)d_in[9];
  const float* w_fc  = (const float*)d_in[10];
  const float* b_fc  = (const float*)d_in[11];
  float* out = (float*)d_out;

  char* ws = (char*)d_ws;
  size_t off = 0;
  auto alloc = [&](size_t bytes) -> void* {
    void* p = ws + off; off += (bytes + 255) & ~(size_t)255; return p;
  };
  int* gcount  = (int*)alloc((size_t)N_GRAPHS*4);
  int* part    = (int*)alloc((size_t)N_GRAPHS*CAP*4);
  int4* whh16  = (int4*)alloc((size_t)8192*16);
  float* proj  = (float*)alloc((size_t)N_GRAPHS*G4*4);
  (void)ws_size; (void)in_sizes; (void)n_in; (void)out_size;

  hipMemsetAsync(gcount, 0, (size_t)N_GRAPHS*4, stream);
  k_part<<<NPART, 256, 0, stream>>>(src, dst, w_hh, gcount, part, whh16);
  k_graph<<<N_GRAPHS, 1024, 0, stream>>>(gcount, part, x, w_gcn, b_gcn, w_ih, b_ih, proj);
  k_lstm<<<BWIN, 512, 0, stream>>>(proj, whh16, b_hh, w_fc, b_fc, out);
}

// Round 6
// 154.550 us; speedup vs baseline: 1.7363x; 1.1089x over previous
//
#include <hip/hip_runtime.h>
#include <hip/hip_bf16.h>

#define N_GRAPHS 200
#define NPG      500
#define NPGP     512
#define N_NODES_ 100000
#define N_EDGES_ 1600000
#define DIN      64
#define DG       128
#define SEQ      20
#define HL       128
#define G4       512
#define BWIN     (N_GRAPHS - SEQ + 1)  // 181
#define NPART    256
#define EPB      (N_EDGES_/NPART)      // 6250
#define SLOTS    64                    // mean 31.25 + ~5.9 sigma; overflow path below
#define CAP      9216

typedef __attribute__((ext_vector_type(8))) short short8;
typedef __attribute__((ext_vector_type(4))) float float4v;
typedef __attribute__((ext_vector_type(2))) _Float16 half2v;

__device__ __forceinline__ float sigmoidf_(float v){ return 1.0f/(1.0f+__expf(-v)); }
__device__ __forceinline__ float tanhf_(float x){
  float e = __expf(2.0f*x);             // inf-safe: x>>0 -> 1, x<<0 -> -1
  return 1.0f - 2.0f/(e + 1.0f);
}

// fp32 -> bf16 round-to-nearest-even
__device__ __forceinline__ unsigned short f2bf(float f) {
  unsigned int u = __float_as_uint(f);
  u += 0x7fffu + ((u >> 16) & 1u);
  return (unsigned short)(u >> 16);
}

__device__ __forceinline__ float h2dot(half2v a, half2v b, float c) {
#if __has_builtin(__builtin_amdgcn_fdot2)
  return __builtin_amdgcn_fdot2(a, b, c, false);
#else
  return c + (float)a.x*(float)b.x + (float)a.y*(float)b.y;
#endif
}

// K1: edge partition. Round-change: 256 blocks x 1024 thr (16 waves/CU, was
// 8) and int2 edge loads -> half the per-(block,graph) global atomics (51K
// vs 102K) and double the latency-hiding waves. w_hh fp32->fp16 on blocks
// 0..7.
__global__ __launch_bounds__(1024) void k_part(const int* __restrict__ src,
                                               const int* __restrict__ dst,
                                               const float* __restrict__ w_hh,
                                               int* __restrict__ gcount,
                                               int* __restrict__ part,
                                               int4* __restrict__ whh16) {
  __shared__ int cnt[N_GRAPHS];
  __shared__ int base[N_GRAPHS];
  __shared__ int buf[N_GRAPHS][SLOTS];   // 51.2 KB
  int b = blockIdx.x, t = threadIdx.x;
  if (b < 8) {                           // whh16[i], i = k4*512 + r
    int i = b*1024 + t;
    int k4 = i >> 9, r = i & 511;
    const float4* wp = (const float4*)(w_hh + (size_t)r*HL + k4*8);
    float4 w0 = wp[0], w1 = wp[1];
    half2v p0 = {(_Float16)w0.x, (_Float16)w0.y};
    half2v p1 = {(_Float16)w0.z, (_Float16)w0.w};
    half2v p2 = {(_Float16)w1.x, (_Float16)w1.y};
    half2v p3 = {(_Float16)w1.z, (_Float16)w1.w};
    int4 pk;
    pk.x = __builtin_bit_cast(int, p0); pk.y = __builtin_bit_cast(int, p1);
    pk.z = __builtin_bit_cast(int, p2); pk.w = __builtin_bit_cast(int, p3);
    whh16[i] = pk;
  }
  if (t < N_GRAPHS) cnt[t] = 0;
  __syncthreads();
  int e0 = b*EPB;
  const int2* s2 = (const int2*)(src + e0);   // e0*4 divisible by 8
  const int2* d2 = (const int2*)(dst + e0);
  for (int i = t; i < EPB/2; i += 1024) {
    int2 ss = s2[i], dd = d2[i];
    {
      int g = ss.x / NPG;
      int pk = ((ss.x - g*NPG) << 9) | (dd.x - g*NPG);
      int pos = atomicAdd(&cnt[g], 1);
      if (pos < SLOTS) buf[g][pos] = pk;
      else { int gp = atomicAdd(&gcount[g], 1); part[g*CAP + gp] = pk; }
    }
    {
      int g = ss.y / NPG;
      int pk = ((ss.y - g*NPG) << 9) | (dd.y - g*NPG);
      int pos = atomicAdd(&cnt[g], 1);
      if (pos < SLOTS) buf[g][pos] = pk;
      else { int gp = atomicAdd(&gcount[g], 1); part[g*CAP + gp] = pk; }
    }
  }
  __syncthreads();
  if (t < N_GRAPHS) base[t] = atomicAdd(&gcount[t], min(cnt[t], SLOTS));
  __syncthreads();
  int w = t >> 6, lane = t & 63;
  for (int g = w; g < N_GRAPHS; g += 16) {
    int n = min(cnt[g], SLOTS);                // n <= 64: one pass
    if (lane < n) part[g*CAP + base[g] + lane] = buf[g][lane];
  }
}

// K2: fused per-graph pipeline, 1024 threads. Round-change: work-queue
// balanced aggregation (initial node = group id, then LDS atomic grab +
// group shfl broadcast) — static 4-nodes/group cost ~+50% from max-of-8
// degree draws per chunk; queue cuts it to ~+5% + ~0.5 µs queue overhead.
// Per-node edge order unchanged -> bit-identical numerics.
__global__ __launch_bounds__(1024) void k_graph(
    const int* __restrict__ gcount, const int* __restrict__ part,
    const float* __restrict__ x,
    const float* __restrict__ w_gcn, const float* __restrict__ b_gcn,
    const float* __restrict__ w_ih,  const float* __restrict__ b_ih,
    float* __restrict__ proj) {
  __shared__ int meta[2048];                    // indeg|outdeg|off|soS; -> pS
  __shared__ int wsum[8];
  __shared__ int qhead;
  __shared__ __align__(16) float hgS[DG];
  __shared__ unsigned short sorted[CAP];        // 18.4 KB; -> wLds overlay
  __shared__ __align__(16) int4 xs[4008];       // 64.1 KB (500 rows + zero row)
  __shared__ __align__(16) int4 hpre[4096];     // 64 KB swizzled
  int* indeg  = meta;
  int* outdeg = meta + 512;
  int* off    = meta + 1024;
  float* soS  = (float*)(meta + 1536);
  int g = blockIdx.x, t = threadIdx.x;
  int lane = t & 63, w = t >> 6;                // w: 0..15

  // early register prefetch of w_gcn (2 float4/thread)
  float4 wg[2];
  #pragma unroll
  for (int q = 0; q < 2; ++q) wg[q] = ((const float4*)w_gcn)[t + q*1024];

  // ---- histogram (part slice cached in registers) ----
  meta[t] = 0; meta[t + 1024] = 0;              // zero indeg+outdeg
  __syncthreads();
  int nseg = gcount[g], seg0 = g*CAP;
  int pr[9];
  #pragma unroll
  for (int q = 0; q < 9; ++q) {
    int e = t + q*1024;
    pr[q] = (e < nseg) ? part[seg0 + e] : -1;
  }
  #pragma unroll
  for (int q = 0; q < 9; ++q) {
    int p = pr[q];
    if (p >= 0) {
      atomicAdd(&indeg[p & 511], 1);
      atomicAdd(&outdeg[p >> 9], 1);
    }
  }
  __syncthreads();
  // ---- exclusive scan over 512 in-degree slots (uniform barriers) ----
  int vscan = 0, scscan = 0;
  if (t < 512) {
    vscan = indeg[t]; scscan = vscan;
    #pragma unroll
    for (int o = 1; o < 64; o <<= 1) { int nn = __shfl_up(scscan, o); if (lane >= o) scscan += nn; }
    if (lane == 63) wsum[w] = scscan;
  }
  __syncthreads();
  if (t < 512) {
    int woff = 0;
    #pragma unroll
    for (int i = 0; i < 8; ++i) woff += (i < w) ? wsum[i] : 0;
    off[t] = woff + scscan - vscan;
    soS[t] = rsqrtf((float)max(outdeg[t], 1));
  }
  __syncthreads();
  // ---- xprep: x * so -> bf16 rows in LDS ----
  const float4* xg = ((const float4*)x) + (size_t)g*8000;
  ushort4* xd = (ushort4*)xs;
  for (int i = t; i < 8000; i += 1024) {
    float4 vv = xg[i];
    float s2 = soS[i >> 4];
    ushort4 u;
    u.x = f2bf(vv.x*s2); u.y = f2bf(vv.y*s2); u.z = f2bf(vv.z*s2); u.w = f2bf(vv.w*s2);
    xd[i] = u;
  }
  if (t < 16) xd[8000 + t] = make_ushort4(0,0,0,0);
  // ---- scatter (from registers) ----
  #pragma unroll
  for (int q = 0; q < 9; ++q) {
    int p = pr[q];
    if (p >= 0) {
      int pos = atomicAdd(&off[p & 511], 1);    // off becomes inclusive end
      sorted[pos] = (unsigned short)(p >> 9);
    }
  }
  if (t == 0) qhead = 128;
  __syncthreads();
  // ---- aggregation: 128 groups x 8 lanes, work-queue balanced ----
  int g8 = lane >> 3, fl = lane & 7;
  int nl = w*8 + g8;                            // initial node = group id
  while (nl < 512) {
    int4 outv = make_int4(0,0,0,0);
    if (nl < NPG) {
      int end = off[nl], dgr = indeg[nl], st = end - dgr;
      float aHi[4] = {0.f,0.f,0.f,0.f};
      float aLo[4] = {0.f,0.f,0.f,0.f};
      int ev = (fl < dgr) ? (int)sorted[st + fl] : 500;
      for (int c0 = 0; c0 < dgr; c0 += 8) {
        int nc = c0 + 8;
        int evn = (nc + fl < dgr) ? (int)sorted[st + nc + fl] : 500;
        #pragma unroll
        for (int j = 0; j < 8; ++j) {
          int se = __shfl(ev, (g8 << 3) + j);
          int4 vv = xs[(se << 3) + fl];
          aHi[0] += __uint_as_float((unsigned)vv.x & 0xffff0000u);
          aLo[0] += __uint_as_float((unsigned)vv.x << 16);
          aHi[1] += __uint_as_float((unsigned)vv.y & 0xffff0000u);
          aLo[1] += __uint_as_float((unsigned)vv.y << 16);
          aHi[2] += __uint_as_float((unsigned)vv.z & 0xffff0000u);
          aLo[2] += __uint_as_float((unsigned)vv.z << 16);
          aHi[3] += __uint_as_float((unsigned)vv.w & 0xffff0000u);
          aLo[3] += __uint_as_float((unsigned)vv.w << 16);
        }
        ev = evn;
      }
      float sn = rsqrtf((float)max(dgr, 1));
      outv.x = (int)(((unsigned)f2bf(aLo[0]*sn)) | ((unsigned)f2bf(aHi[0]*sn) << 16));
      outv.y = (int)(((unsigned)f2bf(aLo[1]*sn)) | ((unsigned)f2bf(aHi[1]*sn) << 16));
      outv.z = (int)(((unsigned)f2bf(aLo[2]*sn)) | ((unsigned)f2bf(aHi[2]*sn) << 16));
      outv.w = (int)(((unsigned)f2bf(aLo[3]*sn)) | ((unsigned)f2bf(aHi[3]*sn) << 16));
    }
    hpre[(nl << 3) + (fl ^ (nl & 7))] = outv;   // swizzled, conflict-free
    int nxt = 0;
    if (fl == 0) nxt = atomicAdd(&qhead, 1);
    nl = __shfl(nxt, (g8 << 3));                // group broadcast
  }
  __syncthreads();
  // ---- stage w_gcn from registers into wLds (overlays sorted, now dead) ----
  unsigned short* wLds = (unsigned short*)sorted;
  #pragma unroll
  for (int q = 0; q < 2; ++q) {
    int i = t + q*1024;
    int k = i >> 5, c4 = (i & 31) << 2;
    int h = k >> 5, j = k & 7, lhi = ((k >> 3) & 3) << 4;
    float vvv[4] = {wg[q].x, wg[q].y, wg[q].z, wg[q].w};
    #pragma unroll
    for (int u = 0; u < 4; ++u) {
      int n = c4 + u;
      int idx = ((n >> 4)*2 + h)*64 + lhi + (n & 15);
      wLds[idx*8 + j] = f2bf(vvv[u]);
    }
  }
  __syncthreads();
  // ---- MFMA GEMM + ReLU + mean pool ----
  float* pS = (float*)meta;                     // 8 KB overlay (meta dead)
  int quad = lane >> 4, l15 = lane & 15;
  float bcol[8];
  #pragma unroll
  for (int nt = 0; nt < 8; ++nt) bcol[nt] = b_gcn[nt*16 + l15];
  float psum[8] = {0.f,0.f,0.f,0.f,0.f,0.f,0.f,0.f};
  #pragma unroll
  for (int i = 0; i < 2; ++i) {
    int row0 = (w + 16*i) << 4;
    int r = row0 + l15;
    int4 a0i = hpre[(r << 3) + (quad ^ (r & 7))];
    int4 a1i = hpre[(r << 3) + ((quad + 4) ^ (r & 7))];
    short8 a0 = *(const short8*)&a0i;
    short8 a1 = *(const short8*)&a1i;
    #pragma unroll
    for (int nt = 0; nt < 8; ++nt) {
      short8 b0 = *((const short8*)&wLds[((nt*2+0)*64 + lane)*8]);
      short8 b1 = *((const short8*)&wLds[((nt*2+1)*64 + lane)*8]);
      float4v acc = {0.f, 0.f, 0.f, 0.f};
      acc = __builtin_amdgcn_mfma_f32_16x16x32_bf16(a0, b0, acc, 0, 0, 0);
      acc = __builtin_amdgcn_mfma_f32_16x16x32_bf16(a1, b1, acc, 0, 0, 0);
      #pragma unroll
      for (int r4 = 0; r4 < 4; ++r4) {
        int node = row0 + quad*4 + r4;
        float vvv = acc[r4] + bcol[nt];
        psum[nt] += (node < NPG) ? fmaxf(vvv, 0.f) : 0.f;
      }
    }
  }
  #pragma unroll
  for (int nt = 0; nt < 8; ++nt) {
    float vvv = psum[nt];
    vvv += __shfl_xor(vvv, 16);
    vvv += __shfl_xor(vvv, 32);
    if (lane < 16) pS[w*DG + nt*16 + lane] = vvv;
  }
  __syncthreads();
  if (t < DG) {
    float sum = 0.f;
    #pragma unroll
    for (int w16 = 0; w16 < 16; ++w16) sum += pS[w16*DG + t];
    hgS[t] = sum * (1.0f/NPG);
  }
  __syncthreads();
  // ---- fused input projection: thread pair -> row t>>1 of w_ih ----
  {
    int r = t >> 1, half = t & 1;
    const float4* wr = (const float4*)(w_ih + (size_t)r*HL) + half*16;
    const float4* hv = (const float4*)hgS + half*16;
    float acc = half ? 0.f : b_ih[r];
    #pragma unroll
    for (int k4 = 0; k4 < 16; ++k4) {
      float4 w4 = wr[k4]; float4 h4 = hv[k4];
      acc += w4.x*h4.x + w4.y*h4.y + w4.z*h4.z + w4.w*h4.w;
    }
    acc += __shfl_xor(acc, 1);
    if (!half) proj[(size_t)g*G4 + r] = acc;
  }
}

// K3: LSTM. Round-change: all 20 proj values prefetched to registers
// (kills the per-step global-load on the serial chain — only ~8 waves/CU
// here, no TLP to hide it) + __expf-based sigmoid/tanh. SEQ loop fully
// unrolled so pj[] indexing is static (rule: runtime-indexed arrays spill).
__global__ __launch_bounds__(512) void k_lstm(const float* __restrict__ proj,
    const int4* __restrict__ whh16, const float* __restrict__ b_hh,
    const float* __restrict__ w_fc, const float* __restrict__ b_fc,
    float* __restrict__ out) {
  __shared__ float gS[G4];
  __shared__ __align__(16) int4 hPi[16];  // 128 fp16 packed h state
  __shared__ float fcS[2];
  int b = blockIdx.x, t = threadIdx.x;
  float pj[SEQ];
  #pragma unroll
  for (int l = 0; l < SEQ; ++l) pj[l] = proj[(size_t)(b+l)*G4 + t];
  int4 W[16];
  #pragma unroll
  for (int k4 = 0; k4 < 16; ++k4) W[k4] = whh16[(k4 << 9) + t];   // coalesced
  if (t < 16) hPi[t] = make_int4(0,0,0,0);
  float bh = b_hh[t];
  float c = 0.f;
  __syncthreads();
  #pragma unroll
  for (int l = 0; l < SEQ; ++l) {
    float a0 = pj[l] + bh;
    float a1 = 0.f, a2 = 0.f, a3 = 0.f;
    #pragma unroll
    for (int k4 = 0; k4 < 16; k4 += 4) {
      int4 hv0 = hPi[k4+0]; int4 hv1 = hPi[k4+1];
      int4 hv2 = hPi[k4+2]; int4 hv3 = hPi[k4+3];
      a0 = h2dot(__builtin_bit_cast(half2v, W[k4+0].x), __builtin_bit_cast(half2v, hv0.x), a0);
      a0 = h2dot(__builtin_bit_cast(half2v, W[k4+0].y), __builtin_bit_cast(half2v, hv0.y), a0);
      a0 = h2dot(__builtin_bit_cast(half2v, W[k4+0].z), __builtin_bit_cast(half2v, hv0.z), a0);
      a0 = h2dot(__builtin_bit_cast(half2v, W[k4+0].w), __builtin_bit_cast(half2v, hv0.w), a0);
      a1 = h2dot(__builtin_bit_cast(half2v, W[k4+1].x), __builtin_bit_cast(half2v, hv1.x), a1);
      a1 = h2dot(__builtin_bit_cast(half2v, W[k4+1].y), __builtin_bit_cast(half2v, hv1.y), a1);
      a1 = h2dot(__builtin_bit_cast(half2v, W[k4+1].z), __builtin_bit_cast(half2v, hv1.z), a1);
      a1 = h2dot(__builtin_bit_cast(half2v, W[k4+1].w), __builtin_bit_cast(half2v, hv1.w), a1);
      a2 = h2dot(__builtin_bit_cast(half2v, W[k4+2].x), __builtin_bit_cast(half2v, hv2.x), a2);
      a2 = h2dot(__builtin_bit_cast(half2v, W[k4+2].y), __builtin_bit_cast(half2v, hv2.y), a2);
      a2 = h2dot(__builtin_bit_cast(half2v, W[k4+2].z), __builtin_bit_cast(half2v, hv2.z), a2);
      a2 = h2dot(__builtin_bit_cast(half2v, W[k4+2].w), __builtin_bit_cast(half2v, hv2.w), a2);
      a3 = h2dot(__builtin_bit_cast(half2v, W[k4+3].x), __builtin_bit_cast(half2v, hv3.x), a3);
      a3 = h2dot(__builtin_bit_cast(half2v, W[k4+3].y), __builtin_bit_cast(half2v, hv3.y), a3);
      a3 = h2dot(__builtin_bit_cast(half2v, W[k4+3].z), __builtin_bit_cast(half2v, hv3.z), a3);
      a3 = h2dot(__builtin_bit_cast(half2v, W[k4+3].w), __builtin_bit_cast(half2v, hv3.w), a3);
    }
    gS[t] = (a0 + a1) + (a2 + a3);
    __syncthreads();
    if (t < 128) {
      float iv = sigmoidf_(gS[t]);
      float fv = sigmoidf_(gS[HL + t]);
      float gv = tanhf_(gS[2*HL + t]);
      float ov = sigmoidf_(gS[3*HL + t]);
      c = fv*c + iv*gv;
      float h = ov * tanhf_(c);
      float hp2 = __shfl_xor(h, 1);           // partner within wave
      if (!(t & 1)) {
        half2v hp = {(_Float16)h, (_Float16)hp2};
        ((int*)hPi)[t >> 1] = __builtin_bit_cast(int, hp);
      }
      if (l == SEQ-1) {
        float s = h * w_fc[t];
        #pragma unroll
        for (int o = 32; o > 0; o >>= 1) s += __shfl_down(s, o);
        if ((t & 63) == 0) fcS[t >> 6] = s;
      }
    }
    __syncthreads();
  }
  if (t == 0) out[b] = fcS[0] + fcS[1] + b_fc[0];
}

extern "C" void kernel_launch(void* const* d_in, const int* in_sizes, int n_in,
                              void* d_out, int out_size, void* d_ws, size_t ws_size,
                              hipStream_t stream) {
  const float* x     = (const float*)d_in[0];
  const int*   src   = (const int*)d_in[1];
  const int*   dst   = (const int*)d_in[2];
  const float* w_gcn = (const float*)d_in[4];
  const float* b_gcn = (const float*)d_in[5];
  const float* w_ih  = (const float*)d_in[6];
  const float* w_hh  = (const float*)d_in[7];
  const float* b_ih  = (const float*)d_in[8];
  const float* b_hh  = (const float*)d_in[9];
  const float* w_fc  = (const float*)d_in[10];
  const float* b_fc  = (const float*)d_in[11];
  float* out = (float*)d_out;

  char* ws = (char*)d_ws;
  size_t off = 0;
  auto alloc = [&](size_t bytes) -> void* {
    void* p = ws + off; off += (bytes + 255) & ~(size_t)255; return p;
  };
  int* gcount  = (int*)alloc((size_t)N_GRAPHS*4);
  int* part    = (int*)alloc((size_t)N_GRAPHS*CAP*4);
  int4* whh16  = (int4*)alloc((size_t)8192*16);
  float* proj  = (float*)alloc((size_t)N_GRAPHS*G4*4);
  (void)ws_size; (void)in_sizes; (void)n_in; (void)out_size;

  hipMemsetAsync(gcount, 0, (size_t)N_GRAPHS*4, stream);
  k_part<<<NPART, 1024, 0, stream>>>(src, dst, w_hh, gcount, part, whh16);
  k_graph<<<N_GRAPHS, 1024, 0, stream>>>(gcount, part, x, w_gcn, b_gcn, w_ih, b_ih, proj);
  k_lstm<<<BWIN, 512, 0, stream>>>(proj, whh16, b_hh, w_fc, b_fc, out);
}